// Round 1
// baseline (22287.309 us; speedup 1.0000x reference)
//
#include <hip/hip_runtime.h>
#include <math.h>

// ---------------- problem constants ----------------
#define BB 2
#define TT 16
#define SS 257
#define DIMD 512
#define DHH 64
#define QHH 16
#define KHH 8
#define DEPTH 8
#define DII 1365          // DI
#define NROWS (BB*TT*SS)  // 8224
#define EPSR 1.1920929e-07f

// ---------------- RMSNorm (optionally permuted read (b,t,s)->(b,s,t)) ----------------
// block = 256 threads, one block per output row. Safe for in-place (out==x, perm=0).
__global__ void rms_kernel(const float* __restrict__ x, const float* __restrict__ w,
                           float* __restrict__ out, int perm) {
    int r = blockIdx.x;
    int src;
    if (perm) {
        int t = r % TT;
        int rs = r / TT;
        int s = rs % SS;
        int b = rs / SS;
        src = (b*TT + t)*SS + s;
    } else {
        src = r;
    }
    const float* xr = x + (size_t)src * DIMD;
    int tid = threadIdx.x;
    float v0 = xr[tid];
    float v1 = xr[tid + 256];
    __shared__ float red[256];
    red[tid] = v0*v0 + v1*v1;
    __syncthreads();
    for (int st = 128; st > 0; st >>= 1) {
        if (tid < st) red[tid] += red[tid + st];
        __syncthreads();
    }
    float scale = rsqrtf(red[0] * (1.0f/DIMD) + EPSR);
    float* orow = out + (size_t)r * DIMD;
    orow[tid]       = v0 * scale * w[tid];
    orow[tid + 256] = v1 * scale * w[tid + 256];
}

// ---------------- generic tiled fp32 GEMM ----------------
// C[nrow,M] = A[nrow,K] @ Bw[K,M] (+bias) ; acc=1 -> C += result
// glu=1: A is [nrow, 2*DII], effective A[r][k] = A[r][k] * gelu(A[r][k+DII]), K must be DII
#define BM 64
#define BN 64
#define BK 16
__global__ void gemm_kernel(const float* __restrict__ A, const float* __restrict__ Bw,
                            const float* __restrict__ bias, float* __restrict__ C,
                            int nrow, int K, int M, int lda, int acc, int glu) {
    __shared__ float As[BK][BM + 4];
    __shared__ float Bs[BK][BN];
    int tid = threadIdx.x;
    int row0 = blockIdx.y * BM;
    int col0 = blockIdx.x * BN;
    int tr = (tid / 16) * 4;
    int tc = (tid % 16) * 4;
    float accv[4][4] = {};
    int atx = tid % 16;   // k offset for A loads
    int aty = tid / 16;   // row 0..15
    int btx = tid % 64;   // col for B loads
    int bty = tid / 64;   // k 0..3
    int nk = (K + BK - 1) / BK;
    for (int kt = 0; kt < nk; ++kt) {
        int k0 = kt * BK;
        #pragma unroll
        for (int i = 0; i < 4; ++i) {
            int rr = row0 + aty + 16*i;
            int kc = k0 + atx;
            float val = 0.f;
            if (rr < nrow && kc < K) {
                if (glu) {
                    float a = A[(size_t)rr*lda + kc];
                    float g = A[(size_t)rr*lda + DII + kc];
                    val = a * (0.5f * g * (1.0f + erff(g * 0.70710678118654752f)));
                } else {
                    val = A[(size_t)rr*lda + kc];
                }
            }
            As[atx][aty + 16*i] = val;
        }
        #pragma unroll
        for (int i = 0; i < 4; ++i) {
            int kk = bty + 4*i;
            int cc = col0 + btx;
            float val = 0.f;
            if ((k0 + kk) < K && cc < M) val = Bw[(size_t)(k0 + kk)*M + cc];
            Bs[kk][btx] = val;
        }
        __syncthreads();
        #pragma unroll
        for (int kk = 0; kk < BK; ++kk) {
            float af[4], bf[4];
            #pragma unroll
            for (int i = 0; i < 4; ++i) af[i] = As[kk][tr + i];
            #pragma unroll
            for (int j = 0; j < 4; ++j) bf[j] = Bs[kk][tc + j];
            #pragma unroll
            for (int i = 0; i < 4; ++i)
                #pragma unroll
                for (int j = 0; j < 4; ++j) accv[i][j] += af[i] * bf[j];
        }
        __syncthreads();
    }
    #pragma unroll
    for (int i = 0; i < 4; ++i) {
        int rr = row0 + tr + i;
        if (rr >= nrow) continue;
        #pragma unroll
        for (int j = 0; j < 4; ++j) {
            int cc = col0 + tc + j;
            if (cc >= M) continue;
            float v = accv[i][j];
            if (bias) v += bias[cc];
            size_t idx = (size_t)rr*M + cc;
            if (acc) C[idx] += v; else C[idx] = v;
        }
    }
}

// ---------------- per-head L2 norm + gamma scale + optional rotary ----------------
// one wave (64 threads) per (row, head); grid = N*heads
__global__ void qknorm_kernel(float* __restrict__ q, const float* __restrict__ gamma,
                              int heads, int rotary) {
    int bid = blockIdx.x;
    int hd = bid % heads;
    int row = bid / heads;
    int d = threadIdx.x;  // 0..63
    size_t idx = ((size_t)row * heads + hd) * DHH + d;
    float v = q[idx];
    float ss = v * v;
    #pragma unroll
    for (int off = 32; off > 0; off >>= 1) ss += __shfl_xor(ss, off);
    float nrm = sqrtf(ss);
    v = v / fmaxf(nrm, 1e-12f);
    v *= (gamma[hd * DHH + d] + 1.0f) * 8.0f;   // sqrt(DH)=8
    if (rotary) {
        int t = row % TT;   // rows are (b,s,t) order for time layers
        float inv = powf(10000.0f, -(float)(d & 31) * (1.0f/32.0f));
        float ang = (float)t * inv;
        float c = cosf(ang), s = sinf(ang);
        float partner = __shfl_xor(v, 32);
        float half = (d < 32) ? -partner : partner;
        v = v * c + half * s;
    }
    q[idx] = v;
}

// ---------------- attention: one block per (batch, qhead, query) ----------------
// q layout [batch*n, QH, DH]; k,v [batch*n, KH, DH]; o [batch*n, QH, DH]
__global__ void attn_kernel(const float* __restrict__ q, const float* __restrict__ k,
                            const float* __restrict__ v, float* __restrict__ o,
                            int n, int causal, int maskspecial) {
    __shared__ float sm[SS + DHH + 256];
    float* scores = sm;
    float* qs = sm + n;
    float* red = qs + DHH;
    int bid = blockIdx.x;
    int i = bid % n;
    int tmp = bid / n;
    int qh = tmp % QHH;
    int b = tmp / QHH;
    int kh = qh >> 1;   // GQA group = 2
    int tid = threadIdx.x;
    const float* qrow = q + (((size_t)b * n + i) * QHH + qh) * DHH;
    if (tid < DHH) qs[tid] = qrow[tid];
    __syncthreads();
    float lmax = -3.4e38f;
    for (int j = tid; j < n; j += 256) {
        const float* krow = k + (((size_t)b * n + j) * KHH + kh) * DHH;
        float dot = 0.f;
        #pragma unroll 8
        for (int d = 0; d < DHH; ++d) dot += qs[d] * krow[d];
        float s = dot * 0.125f;                 // DH^-0.5
        s = tanhf(s * 0.02f) * 50.0f;           // softclamp
        if (causal && j > i) s = -3.0e38f;
        if (maskspecial && (i < n-1) && (j >= n-1)) s = -3.0e38f;
        scores[j] = s;
        lmax = fmaxf(lmax, s);
    }
    red[tid] = lmax; __syncthreads();
    for (int st = 128; st > 0; st >>= 1) {
        if (tid < st) red[tid] = fmaxf(red[tid], red[tid + st]);
        __syncthreads();
    }
    float mx = red[0];
    __syncthreads();
    float lsum = 0.f;
    for (int j = tid; j < n; j += 256) {
        float p = expf(scores[j] - mx);
        scores[j] = p;
        lsum += p;
    }
    red[tid] = lsum; __syncthreads();
    for (int st = 128; st > 0; st >>= 1) {
        if (tid < st) red[tid] += red[tid + st];
        __syncthreads();
    }
    float invs = 1.0f / red[0];
    __syncthreads();
    // P @ V
    int d = tid & 63;
    int slice = tid >> 6;
    float acc = 0.f;
    for (int j = slice; j < n; j += 4) {
        acc += scores[j] * v[(((size_t)b * n + j) * KHH + kh) * DHH + d];
    }
    red[tid] = acc; __syncthreads();
    if (slice == 0) {
        float r = red[d] + red[64 + d] + red[128 + d] + red[192 + d];
        o[(((size_t)b * n + i) * QHH + qh) * DHH + d] = r * invs;
    }
}

// ---------------- residual add with optional (b,s,t)->(b,t,s) scatter ----------------
__global__ void addperm_kernel(float* __restrict__ x, const float* __restrict__ o2, int perm) {
    size_t idx = (size_t)blockIdx.x * 256 + threadIdx.x;
    if (idx >= (size_t)NROWS * DIMD) return;
    int c = (int)(idx % DIMD);
    int r = (int)(idx / DIMD);
    int xrow;
    if (perm) {
        int t = r % TT;
        int rs = r / TT;
        int s = rs % SS;
        int b = rs / SS;
        xrow = (b*TT + t)*SS + s;
    } else {
        xrow = r;
    }
    x[(size_t)xrow * DIMD + c] += o2[idx];
}

// ---------------- host-side launch ----------------
extern "C" void kernel_launch(void* const* d_in, const int* in_sizes, int n_in,
                              void* d_out, int out_size, void* d_ws, size_t ws_size,
                              hipStream_t stream) {
    const float* tokens      = (const float*)d_in[0];
    const float* attn_norm_w = (const float*)d_in[1];
    const float* Wq          = (const float*)d_in[2];
    const float* Wk          = (const float*)d_in[3];
    const float* Wv          = (const float*)d_in[4];
    const float* q_gamma     = (const float*)d_in[5];
    const float* k_gamma     = (const float*)d_in[6];
    const float* Wo          = (const float*)d_in[7];
    const float* ff_norm_w   = (const float*)d_in[8];
    const float* W_in        = (const float*)d_in[9];
    const float* b_in        = (const float*)d_in[10];
    const float* W_out       = (const float*)d_in[11];
    const float* b_out       = (const float*)d_in[12];
    const float* final_w     = (const float*)d_in[13];

    float* x = (float*)d_out;                      // residual stream lives in d_out
    char* ws = (char*)d_ws;
    const size_t sz_row = (size_t)NROWS * 4;

    float* h  = (float*)(ws);                                  // [N,512]
    char* region = ws + sz_row * DIMD;
    float* qb = (float*)(region);                              // [N,1024]
    float* kb = (float*)(region + sz_row * 1024);              // [N,512]
    float* vb = (float*)(region + sz_row * (1024 + 512));      // [N,512]
    float* ob = (float*)(region + sz_row * (1024 + 1024));     // [N,1024]
    float* o2 = (float*)(region + sz_row * (1024 + 1024 + 1024)); // [N,512] (time layers)
    float* fb = (float*)(region);                              // [N,2730] (FF phase, aliases q/k/v)

    hipMemcpyAsync(x, tokens, sz_row * DIMD, hipMemcpyDeviceToDevice, stream);

    const int GY = (NROWS + BM - 1) / BM;   // 129
    for (int l = 0; l < DEPTH; ++l) {
        int is_time = ((l + 1) % 4 == 0) ? 1 : 0;
        const float* anw = attn_norm_w + (size_t)l * DIMD;
        const float* wq  = Wq  + (size_t)l * DIMD * (QHH*DHH);
        const float* wk  = Wk  + (size_t)l * DIMD * (KHH*DHH);
        const float* wv  = Wv  + (size_t)l * DIMD * (KHH*DHH);
        const float* qg  = q_gamma + (size_t)l * QHH * DHH;
        const float* kg  = k_gamma + (size_t)l * KHH * DHH;
        const float* wo  = Wo  + (size_t)l * (QHH*DHH) * DIMD;
        const float* fnw = ff_norm_w + (size_t)l * DIMD;
        const float* win = W_in + (size_t)l * DIMD * (2*DII);
        const float* bin = b_in + (size_t)l * (2*DII);
        const float* wout= W_out + (size_t)l * DII * DIMD;
        const float* bout= b_out + (size_t)l * DIMD;

        // ---- attention block ----
        rms_kernel<<<NROWS, 256, 0, stream>>>(x, anw, h, is_time);
        gemm_kernel<<<dim3(1024/BN, GY), 256, 0, stream>>>(h, wq, nullptr, qb, NROWS, 512, 1024, 512, 0, 0);
        gemm_kernel<<<dim3( 512/BN, GY), 256, 0, stream>>>(h, wk, nullptr, kb, NROWS, 512,  512, 512, 0, 0);
        gemm_kernel<<<dim3( 512/BN, GY), 256, 0, stream>>>(h, wv, nullptr, vb, NROWS, 512,  512, 512, 0, 0);
        qknorm_kernel<<<NROWS * QHH, 64, 0, stream>>>(qb, qg, QHH, is_time);
        qknorm_kernel<<<NROWS * KHH, 64, 0, stream>>>(kb, kg, KHH, is_time);
        if (is_time) {
            // batch = B*S = 514, n = T = 16, causal, rotary already applied
            attn_kernel<<<(BB*SS) * QHH * TT, 256, 0, stream>>>(qb, kb, vb, ob, TT, 1, 0);
            gemm_kernel<<<dim3(512/BN, GY), 256, 0, stream>>>(ob, wo, nullptr, o2, NROWS, 1024, 512, 1024, 0, 0);
            addperm_kernel<<<(NROWS*DIMD + 255)/256, 256, 0, stream>>>(x, o2, 1);
        } else {
            // batch = B*T = 32, n = S = 257, special-token mask
            attn_kernel<<<(BB*TT) * QHH * SS, 256, 0, stream>>>(qb, kb, vb, ob, SS, 0, 1);
            gemm_kernel<<<dim3(512/BN, GY), 256, 0, stream>>>(ob, wo, nullptr, x, NROWS, 1024, 512, 1024, 1, 0);
        }

        // ---- feed-forward block ----
        rms_kernel<<<NROWS, 256, 0, stream>>>(x, fnw, h, 0);
        gemm_kernel<<<dim3((2*DII + BN - 1)/BN, GY), 256, 0, stream>>>(h, win, bin, fb, NROWS, 512, 2*DII, 512, 0, 0);
        // W_out GEMM with GLU fused into the A-operand load
        gemm_kernel<<<dim3(512/BN, GY), 256, 0, stream>>>(fb, wout, bout, x, NROWS, DII, 512, 2*DII, 1, 1);
    }

    // final RMSNorm, in place on d_out
    rms_kernel<<<NROWS, 256, 0, stream>>>(x, final_w, x, 0);
}

// Round 2
// 3505.741 us; speedup vs baseline: 6.3574x; 6.3574x over previous
//
#include <hip/hip_runtime.h>
#include <hip/hip_bf16.h>
#include <math.h>

typedef __attribute__((ext_vector_type(8))) short short8;
typedef __attribute__((ext_vector_type(4))) float f32x4;
typedef __hip_bfloat16 bf16;

#define BB 2
#define TT 16
#define SSQ 257
#define DIMD 512
#define NROWS 8224          // B*T*S
#define DII 1365
#define DI2 2730
#define FBLD 2816           // fb row stride (N padded to 22*128)
#define GLULD 1376          // glu row stride (K padded to 43*32)
#define SKP 288             // padded key count for space attn
#define EPSR 1.1920929e-07f

__device__ __forceinline__ void async16(const void* g, const void* l) {
    __builtin_amdgcn_global_load_lds(
        (const __attribute__((address_space(1))) void*)g,
        (__attribute__((address_space(3))) void*)l, 16, 0, 0);
}

__device__ __forceinline__ short f2bfs(float x) {
    bf16 h = __float2bfloat16(x);
    return *reinterpret_cast<short*>(&h);
}

// ---------------- weight transpose + fp32->bf16 (zero-padded) ----------------
// W [K][M] fp32  ->  Wt [Npad][Kpad] bf16 ; grid (Kpad/32, Npad/32), block 256
__global__ void wtrans_kernel(const float* __restrict__ W, bf16* __restrict__ Wt,
                              int K, int M, int Kpad) {
    __shared__ float tile[32][33];
    int k0 = blockIdx.x * 32, m0 = blockIdx.y * 32;
    int tx = threadIdx.x & 31, ty = threadIdx.x >> 5;
    #pragma unroll
    for (int i = 0; i < 4; ++i) {
        int k = k0 + ty + 8 * i, m = m0 + tx;
        tile[ty + 8 * i][tx] = (k < K && m < M) ? W[(size_t)k * M + m] : 0.f;
    }
    __syncthreads();
    #pragma unroll
    for (int i = 0; i < 4; ++i) {
        int m = m0 + ty + 8 * i, k = k0 + tx;
        Wt[(size_t)m * Kpad + k] = __float2bfloat16(tile[tx][ty + 8 * i]);
    }
}

// ---------------- RMSNorm (optional permuted read (b,t,s)->(b,s,t)) ----------------
template<int BF16OUT>
__global__ void rms_kernel(const float* __restrict__ x, const float* __restrict__ w,
                           void* __restrict__ out, int perm) {
    int r = blockIdx.x;
    int src = r;
    if (perm) {
        int t = r & 15; int rs = r >> 4; int s = rs % SSQ; int b = rs / SSQ;
        src = (b * TT + t) * SSQ + s;
    }
    const float* xr = x + (size_t)src * DIMD;
    int tid = threadIdx.x;
    float v0 = xr[tid], v1 = xr[tid + 256];
    __shared__ float red[256];
    red[tid] = v0 * v0 + v1 * v1;
    __syncthreads();
    for (int st = 128; st; st >>= 1) {
        if (tid < st) red[tid] += red[tid + st];
        __syncthreads();
    }
    float sc = rsqrtf(red[0] * (1.f / DIMD) + EPSR);
    if (BF16OUT) {
        bf16* o = (bf16*)out + (size_t)r * DIMD;
        o[tid] = __float2bfloat16(v0 * sc * w[tid]);
        o[tid + 256] = __float2bfloat16(v1 * sc * w[tid + 256]);
    } else {
        float* o = (float*)out + (size_t)r * DIMD;
        o[tid] = v0 * sc * w[tid];
        o[tid + 256] = v1 * sc * w[tid + 256];
    }
}

// ---------------- MFMA bf16 GEMM: C[nrow,M] = A[nrow,K] @ Bt[M,K]^T ----------------
// 128x128 tile, BK=32, 4 waves (2x2 of 64x64), global_load_lds staging with
// XOR chunk swizzle f(m,kg)=m*4+(kg^(m&3)) so frag ds_read_b128 is 2-way (free).
template<int OUTBF16, int PERM>
__global__ __launch_bounds__(256)
void mfma_gemm(const bf16* __restrict__ A, int lda,
               const bf16* __restrict__ Bt, int ldb,
               const float* __restrict__ bias,
               void* __restrict__ C, int ldc, int Mstore,
               int nrow, int K) {
    __shared__ __align__(16) short lds_a[128 * 32];
    __shared__ __align__(16) short lds_b[128 * 32];
    int tid = threadIdx.x;
    int wave = tid >> 6, lane = tid & 63;
    int quad = lane >> 4, l16 = lane & 15;
    int m0 = blockIdx.y * 128, n0 = blockIdx.x * 128;
    int wm = (wave & 1) * 64, wn = (wave >> 1) * 64;
    f32x4 zero4 = {0.f, 0.f, 0.f, 0.f};
    f32x4 acc[4][4];
    #pragma unroll
    for (int i = 0; i < 4; ++i)
        #pragma unroll
        for (int j = 0; j < 4; ++j) acc[i][j] = zero4;

    int ca0 = (wave * 2 + 0) * 64 + lane;
    int ca1 = (wave * 2 + 1) * 64 + lane;
    int am0 = ca0 >> 2, ak0 = (ca0 & 3) ^ (am0 & 3);
    int am1 = ca1 >> 2, ak1 = (ca1 & 3) ^ (am1 & 3);
    int ar0 = m0 + am0; if (ar0 >= nrow) ar0 = nrow - 1;
    int ar1 = m0 + am1; if (ar1 >= nrow) ar1 = nrow - 1;
    const short* Ap = (const short*)A;
    const short* Bp = (const short*)Bt;
    const short* ga0 = Ap + (size_t)ar0 * lda + ak0 * 8;
    const short* ga1 = Ap + (size_t)ar1 * lda + ak1 * 8;
    const short* gb0 = Bp + (size_t)(n0 + am0) * ldb + ak0 * 8;
    const short* gb1 = Bp + (size_t)(n0 + am1) * ldb + ak1 * 8;
    short* la0 = &lds_a[(wave * 2 + 0) * 64 * 8];
    short* la1 = &lds_a[(wave * 2 + 1) * 64 * 8];
    short* lb0 = &lds_b[(wave * 2 + 0) * 64 * 8];
    short* lb1 = &lds_b[(wave * 2 + 1) * 64 * 8];
    int sxa = quad ^ (l16 & 3);

    int nk = K >> 5;
    for (int kt = 0; kt < nk; ++kt) {
        int k0 = kt * 32;
        async16(ga0 + k0, la0);
        async16(ga1 + k0, la1);
        async16(gb0 + k0, lb0);
        async16(gb1 + k0, lb1);
        __syncthreads();
        short8 af[4], bfr[4];
        #pragma unroll
        for (int mi = 0; mi < 4; ++mi) {
            int ml = wm + mi * 16 + l16;
            af[mi] = *(const short8*)&lds_a[(ml * 4 + sxa) * 8];
        }
        #pragma unroll
        for (int nj = 0; nj < 4; ++nj) {
            int nl = wn + nj * 16 + l16;
            bfr[nj] = *(const short8*)&lds_b[(nl * 4 + sxa) * 8];
        }
        #pragma unroll
        for (int mi = 0; mi < 4; ++mi)
            #pragma unroll
            for (int nj = 0; nj < 4; ++nj)
                acc[mi][nj] = __builtin_amdgcn_mfma_f32_16x16x32_bf16(
                    af[mi], bfr[nj], acc[mi][nj], 0, 0, 0);
        __syncthreads();
    }

    #pragma unroll
    for (int mi = 0; mi < 4; ++mi) {
        #pragma unroll
        for (int e = 0; e < 4; ++e) {
            int row = m0 + wm + mi * 16 + quad * 4 + e;
            if (row >= nrow) continue;
            int orow = row;
            if (PERM) {
                int t = row & 15; int rs = row >> 4; int s = rs % SSQ; int b = rs / SSQ;
                orow = (b * TT + t) * SSQ + s;
            }
            #pragma unroll
            for (int nj = 0; nj < 4; ++nj) {
                int col = n0 + wn + nj * 16 + l16;
                if (col >= Mstore) continue;
                float v = acc[mi][nj][e];
                if (bias) v += bias[col];
                if (OUTBF16) {
                    ((bf16*)C)[(size_t)row * ldc + col] = __float2bfloat16(v);
                } else {
                    float* p = (float*)C + (size_t)orow * ldc + col;
                    *p += v;
                }
            }
        }
    }
}

// ---------------- fused q/k l2norm + gamma + optional rotary ----------------
// qkv [row][2048] bf16: q at cols 0..1023, k at 1024..1535, v at 1536..2047
__global__ void qknorm_kernel(bf16* __restrict__ qkv, const float* __restrict__ qg,
                              const float* __restrict__ kg, int rotary) {
    int row = blockIdx.x, hd = blockIdx.y;
    int d = threadIdx.x;
    const float* gamma; int col;
    if (hd < 16) { gamma = qg + hd * 64; col = hd * 64; }
    else         { gamma = kg + (hd - 16) * 64; col = 1024 + (hd - 16) * 64; }
    bf16* p = qkv + (size_t)row * 2048 + col + d;
    float v = __bfloat162float(*p);
    float ss = v * v;
    #pragma unroll
    for (int off = 32; off; off >>= 1) ss += __shfl_xor(ss, off);
    v = v / fmaxf(sqrtf(ss), 1e-12f);
    v *= (gamma[d] + 1.0f) * 8.0f;   // sqrt(DH)=8
    if (rotary) {
        int t = row & 15;   // rows in (b,s,t) order
        float inv = powf(10000.f, -(float)(d & 31) * (1.f / 32.f));
        float ang = (float)t * inv;
        float cs = __cosf(ang), sn = __sinf(ang);
        float partner = __shfl_xor(v, 32);
        float half = (d < 32) ? -partner : partner;
        v = v * cs + half * sn;
    }
    *p = __float2bfloat16(v);
}

// ---------------- V transpose for PV MFMA: vt[bt*8+kh][64][SKP] bf16 ----------------
__global__ void vtrans_kernel(const bf16* __restrict__ qkv, bf16* __restrict__ vt) {
    int bkh = blockIdx.x;          // bt*8 + kh
    int kc = blockIdx.y;           // key chunk of 32
    int bt = bkh >> 3, kh = bkh & 7;
    int tid = threadIdx.x;
    #pragma unroll
    for (int i = 0; i < 8; ++i) {
        int idx = tid + 256 * i;   // 0..2047
        int kl = idx >> 6;         // key local
        int d = idx & 63;
        int key = kc * 32 + kl;
        float v = 0.f;
        if (key < SSQ)
            v = __bfloat162float(qkv[((size_t)(bt * SSQ + key)) * 2048 + 1536 + kh * 64 + d]);
        vt[((size_t)bkh * 64 + d) * SKP + key] = __float2bfloat16(v);
    }
}

// ---------------- space attention: MFMA QK^T + softmax + MFMA PV ----------------
// grid (9, 16, 32) = (q32-tile, qh, bt); block 128 (2 waves, 16 q-rows each)
__global__ __launch_bounds__(128)
void space_attn_kernel(const bf16* __restrict__ qkv, const bf16* __restrict__ vt,
                       bf16* __restrict__ ob) {
    __shared__ __align__(16) float scores[2][16][292];
    __shared__ float rowinv[2][16];
    int qt = blockIdx.x, qh = blockIdx.y, bt = blockIdx.z;
    int kh = qh >> 1;
    int tid = threadIdx.x, wave = tid >> 6, lane = tid & 63;
    int quad = lane >> 4, l16 = lane & 15;
    int q0 = qt * 32 + wave * 16;
    int qi = q0 + l16; int qic = qi > 256 ? 256 : qi;
    const short* qp = (const short*)qkv + ((size_t)(bt * SSQ + qic)) * 2048 + qh * 64;
    short8 a0 = *(const short8*)(qp + quad * 8);
    short8 a1 = *(const short8*)(qp + 32 + quad * 8);
    const short* kbp = (const short*)qkv + (size_t)bt * SSQ * 2048 + 1024 + kh * 64;
    f32x4 zero4 = {0.f, 0.f, 0.f, 0.f};
    for (int kt = 0; kt < 18; ++kt) {
        int key = kt * 16 + l16; int keyc = key > 256 ? 256 : key;
        const short* kp = kbp + (size_t)keyc * 2048;
        short8 b0 = *(const short8*)(kp + quad * 8);
        short8 b1 = *(const short8*)(kp + 32 + quad * 8);
        f32x4 c = zero4;
        c = __builtin_amdgcn_mfma_f32_16x16x32_bf16(a0, b0, c, 0, 0, 0);
        c = __builtin_amdgcn_mfma_f32_16x16x32_bf16(a1, b1, c, 0, 0, 0);
        int j = kt * 16 + l16;
        #pragma unroll
        for (int e = 0; e < 4; ++e) {
            int qq = q0 + quad * 4 + e;
            float s = c[e] * 0.125f;
            float ex = __expf(s * 0.04f);           // tanh(s/50)*50 softclamp
            s = 50.f * (ex - 1.f) / (ex + 1.f);
            if (j > 256 || (qq < 256 && j == 256)) s = -1e30f;
            scores[wave][quad * 4 + e][j ^ (e * 8)] = s;  // XOR swizzle (bits 3-4)
        }
    }
    __syncthreads();
    {   // softmax: r = lane>>2, 4 lanes per row scan 72 cols each
        int r = lane >> 2, p4 = lane & 3;
        float mx = -1e30f;
        for (int t = 0; t < 72; ++t) mx = fmaxf(mx, scores[wave][r][p4 + 4 * t]);
        mx = fmaxf(mx, __shfl_xor(mx, 1));
        mx = fmaxf(mx, __shfl_xor(mx, 2));
        float sum = 0.f;
        for (int t = 0; t < 72; ++t) {
            float p = __expf(scores[wave][r][p4 + 4 * t] - mx);
            scores[wave][r][p4 + 4 * t] = p;
            sum += p;
        }
        sum += __shfl_xor(sum, 1);
        sum += __shfl_xor(sum, 2);
        if (p4 == 0) rowinv[wave][r] = 1.f / sum;
    }
    __syncthreads();
    // PV
    f32x4 oacc[4];
    #pragma unroll
    for (int nt = 0; nt < 4; ++nt) oacc[nt] = zero4;
    int sw = (quad ^ (l16 & 3)) * 8;   // un-swizzle for A-frag reads
    const short* vbp = (const short*)vt + ((size_t)(bt * 8 + kh) * 64) * SKP;
    for (int kc = 0; kc < 9; ++kc) {
        const float* prow = &scores[wave][l16][kc * 32 + sw];
        f32x4 p0 = *(const f32x4*)prow;
        f32x4 p1 = *(const f32x4*)(prow + 4);
        short8 af;
        #pragma unroll
        for (int j = 0; j < 4; ++j) af[j] = f2bfs(p0[j]);
        #pragma unroll
        for (int j = 0; j < 4; ++j) af[4 + j] = f2bfs(p1[j]);
        #pragma unroll
        for (int nt = 0; nt < 4; ++nt) {
            short8 bv = *(const short8*)(vbp + (size_t)(nt * 16 + l16) * SKP + kc * 32 + quad * 8);
            oacc[nt] = __builtin_amdgcn_mfma_f32_16x16x32_bf16(af, bv, oacc[nt], 0, 0, 0);
        }
    }
    #pragma unroll
    for (int e = 0; e < 4; ++e) {
        int q = q0 + quad * 4 + e;
        if (q >= SSQ) continue;
        float inv = rowinv[wave][quad * 4 + e];
        bf16* op = ob + ((size_t)(bt * SSQ + q)) * 1024 + qh * 64;
        #pragma unroll
        for (int nt = 0; nt < 4; ++nt)
            op[nt * 16 + l16] = __float2bfloat16(oacc[nt][e] * inv);
    }
}

// ---------------- time attention (n=16, causal): one block per (b*s, qh) ----------------
__global__ void time_attn_kernel(const bf16* __restrict__ qkv, bf16* __restrict__ ob) {
    __shared__ float qs[16][65], ks[16][65], ps[16][17];
    int bs = blockIdx.x, qh = blockIdx.y, kh = qh >> 1;
    int tid = threadIdx.x;
    size_t rowbase = (size_t)bs * 16;
    #pragma unroll
    for (int i = 0; i < 4; ++i) {
        int idx = tid + 256 * i;
        int r = idx >> 6, d = idx & 63;
        qs[r][d] = __bfloat162float(qkv[(rowbase + r) * 2048 + qh * 64 + d]);
        ks[r][d] = __bfloat162float(qkv[(rowbase + r) * 2048 + 1024 + kh * 64 + d]);
    }
    __syncthreads();
    int i = tid >> 4, j = tid & 15;
    float dot = 0.f;
    #pragma unroll 16
    for (int d = 0; d < 64; ++d) dot += qs[i][d] * ks[j][d];
    float s = dot * 0.125f;
    float ex = __expf(s * 0.04f);
    s = 50.f * (ex - 1.f) / (ex + 1.f);
    if (j > i) s = -1e30f;
    float mx = s;
    mx = fmaxf(mx, __shfl_xor(mx, 1));
    mx = fmaxf(mx, __shfl_xor(mx, 2));
    mx = fmaxf(mx, __shfl_xor(mx, 4));
    mx = fmaxf(mx, __shfl_xor(mx, 8));
    float p = __expf(s - mx);
    float sum = p;
    sum += __shfl_xor(sum, 1);
    sum += __shfl_xor(sum, 2);
    sum += __shfl_xor(sum, 4);
    sum += __shfl_xor(sum, 8);
    ps[i][j] = p / sum;
    __syncthreads();
    #pragma unroll
    for (int ii = 0; ii < 4; ++ii) {
        int idx = tid + 256 * ii;
        int r = idx >> 6, d = idx & 63;
        float acc = 0.f;
        #pragma unroll
        for (int jj = 0; jj < 16; ++jj)
            acc += ps[r][jj] * __bfloat162float(qkv[(rowbase + jj) * 2048 + 1536 + kh * 64 + d]);
        ob[(rowbase + r) * 1024 + qh * 64 + d] = __float2bfloat16(acc);
    }
}

// ---------------- GLU: glu[r][c] = a * gelu_exact(g), bf16, zero-padded to 1376 ----------------
__global__ void glu_kernel(const bf16* __restrict__ fb, bf16* __restrict__ glu) {
    size_t idx = (size_t)blockIdx.x * 256 + threadIdx.x;
    if (idx >= (size_t)NROWS * GLULD) return;
    int c = (int)(idx % GLULD);
    size_t r = idx / GLULD;
    float v = 0.f;
    if (c < DII) {
        float a = __bfloat162float(fb[r * FBLD + c]);
        float g = __bfloat162float(fb[r * FBLD + DII + c]);
        v = a * 0.5f * g * (1.f + erff(g * 0.70710678118654752f));
    }
    glu[r * GLULD + c] = __float2bfloat16(v);
}

// ---------------- host-side launch ----------------
extern "C" void kernel_launch(void* const* d_in, const int* in_sizes, int n_in,
                              void* d_out, int out_size, void* d_ws, size_t ws_size,
                              hipStream_t stream) {
    const float* tokens      = (const float*)d_in[0];
    const float* attn_norm_w = (const float*)d_in[1];
    const float* Wq          = (const float*)d_in[2];
    const float* Wk          = (const float*)d_in[3];
    const float* Wv          = (const float*)d_in[4];
    const float* q_gamma     = (const float*)d_in[5];
    const float* k_gamma     = (const float*)d_in[6];
    const float* Wo          = (const float*)d_in[7];
    const float* ff_norm_w   = (const float*)d_in[8];
    const float* W_in        = (const float*)d_in[9];
    const float* b_in        = (const float*)d_in[10];
    const float* W_out       = (const float*)d_in[11];
    const float* b_out       = (const float*)d_in[12];
    const float* final_w     = (const float*)d_in[13];

    float* x = (float*)d_out;
    char* ws = (char*)d_ws;

    // per-layer bf16 weight slab (reused): qkv^T [2048][512], Wo^T [512][1024],
    // Win^T [2816][512], Wout^T [512][1376]
    bf16* wtqkv = (bf16*)ws;
    bf16* wto   = wtqkv + 2048 * 512;
    bf16* wtin  = wto   + 512 * 1024;
    bf16* wtout = wtin  + 2816 * 512;
    size_t off = (size_t)(2048 * 512 + 512 * 1024 + 2816 * 512 + 512 * 1376) * 2;  // 7,438,336 B
    bf16* h = (bf16*)(ws + off);
    off += (size_t)NROWS * 512 * 2;
    char* region = ws + off;
    // attention phase
    bf16* qkv = (bf16*)region;                               // 33,685,504 B
    bf16* vt  = (bf16*)(region + 33685504);                  //  9,437,184 B
    bf16* ob  = (bf16*)(region + 33685504 + 9437184);        // 16,842,752 B
    // FF phase (aliases attention buffers)
    bf16* fb  = (bf16*)region;                               // 46,317,568 B
    bf16* glu = (bf16*)(region + 46317568);                  // 22,632,448 B

    hipMemcpyAsync(x, tokens, (size_t)NROWS * 512 * 4, hipMemcpyDeviceToDevice, stream);

    for (int l = 0; l < 8; ++l) {
        int is_time = ((l + 1) % 4 == 0) ? 1 : 0;
        // weight convert + transpose (bf16)
        wtrans_kernel<<<dim3(16, 32), 256, 0, stream>>>(Wq + (size_t)l * 512 * 1024, wtqkv, 512, 1024, 512);
        wtrans_kernel<<<dim3(16, 16), 256, 0, stream>>>(Wk + (size_t)l * 512 * 512, wtqkv + 1024 * 512, 512, 512, 512);
        wtrans_kernel<<<dim3(16, 16), 256, 0, stream>>>(Wv + (size_t)l * 512 * 512, wtqkv + 1536 * 512, 512, 512, 512);
        wtrans_kernel<<<dim3(32, 16), 256, 0, stream>>>(Wo + (size_t)l * 1024 * 512, wto, 1024, 512, 1024);
        wtrans_kernel<<<dim3(16, 88), 256, 0, stream>>>(W_in + (size_t)l * 512 * 2730, wtin, 512, 2730, 512);
        wtrans_kernel<<<dim3(43, 16), 256, 0, stream>>>(W_out + (size_t)l * 1365 * 512, wtout, 1365, 512, 1376);

        // ---- attention block ----
        rms_kernel<1><<<NROWS, 256, 0, stream>>>(x, attn_norm_w + (size_t)l * 512, h, is_time);
        mfma_gemm<1, 0><<<dim3(16, 65), 256, 0, stream>>>(h, 512, wtqkv, 512, nullptr,
                                                          qkv, 2048, 2048, NROWS, 512);
        qknorm_kernel<<<dim3(NROWS, 24), 64, 0, stream>>>(qkv, q_gamma + (size_t)l * 1024,
                                                          k_gamma + (size_t)l * 512, is_time);
        if (is_time) {
            time_attn_kernel<<<dim3(514, 16), 256, 0, stream>>>(qkv, ob);
            mfma_gemm<0, 1><<<dim3(4, 65), 256, 0, stream>>>(ob, 1024, wto, 1024, nullptr,
                                                             x, 512, 512, NROWS, 1024);
        } else {
            vtrans_kernel<<<dim3(256, 9), 256, 0, stream>>>(qkv, vt);
            space_attn_kernel<<<dim3(9, 16, 32), 128, 0, stream>>>(qkv, vt, ob);
            mfma_gemm<0, 0><<<dim3(4, 65), 256, 0, stream>>>(ob, 1024, wto, 1024, nullptr,
                                                             x, 512, 512, NROWS, 1024);
        }

        // ---- feed-forward block ----
        rms_kernel<1><<<NROWS, 256, 0, stream>>>(x, ff_norm_w + (size_t)l * 512, h, 0);
        mfma_gemm<1, 0><<<dim3(22, 65), 256, 0, stream>>>(h, 512, wtin, 512, b_in + (size_t)l * DI2,
                                                          fb, FBLD, DI2, NROWS, 512);
        glu_kernel<<<((size_t)NROWS * GLULD + 255) / 256, 256, 0, stream>>>(fb, glu);
        mfma_gemm<0, 0><<<dim3(4, 65), 256, 0, stream>>>(glu, GLULD, wtout, GLULD, b_out + (size_t)l * 512,
                                                         x, 512, 512, NROWS, GLULD);
    }

    rms_kernel<0><<<NROWS, 256, 0, stream>>>(x, final_w, x, 0);
}

// Round 3
// 2856.594 us; speedup vs baseline: 7.8021x; 1.2272x over previous
//
#include <hip/hip_runtime.h>
#include <hip/hip_bf16.h>
#include <math.h>

typedef __attribute__((ext_vector_type(8))) short short8;
typedef __attribute__((ext_vector_type(4))) float f32x4;
typedef __hip_bfloat16 bf16;

#define BB 2
#define TT 16
#define SSQ 257
#define DIMD 512
#define NROWS 8224          // B*T*S
#define DII 1365
#define DI2 2730
#define FNPAD 2816          // ff_in N padded (22*128), interleaved a/g pairs
#define GLULD 1408          // glu row stride / ff_out K (44*32)
#define SKP 288             // padded key count for space attn
#define EPSR 1.1920929e-07f

__device__ __forceinline__ void async16(const void* g, const void* l) {
    __builtin_amdgcn_global_load_lds(
        (const __attribute__((address_space(1))) void*)g,
        (__attribute__((address_space(3))) void*)l, 16, 0, 0);
}

__device__ __forceinline__ short f2bfs(float x) {
    bf16 h = __float2bfloat16(x);
    return *reinterpret_cast<short*>(&h);
}

// ---------------- batched per-layer weight transpose fp32->bf16 ----------------
// Segments (flattened 32x32 tiles): Wq 512 | Wk 256 | Wv 256 | Wo 512 | Win 1408
// (column-interleaved a/g) | Wout 704  => grid 3648, block 256.
__global__ void wtrans_layer(const float* __restrict__ wq, const float* __restrict__ wk,
                             const float* __restrict__ wv, const float* __restrict__ wo,
                             const float* __restrict__ win, const float* __restrict__ wout,
                             bf16* __restrict__ dqkv, bf16* __restrict__ dwo,
                             bf16* __restrict__ dwin, bf16* __restrict__ dwout) {
    __shared__ float tile[32][33];
    int bid = blockIdx.x;
    const float* src; bf16* dst; int K, M, Kpad, interleave = 0, local;
    if (bid < 512)       { src = wq;   dst = dqkv;            K = 512;  M = 1024; Kpad = 512;  local = bid; }
    else if (bid < 768)  { src = wk;   dst = dqkv + 1024*512; K = 512;  M = 512;  Kpad = 512;  local = bid - 512; }
    else if (bid < 1024) { src = wv;   dst = dqkv + 1536*512; K = 512;  M = 512;  Kpad = 512;  local = bid - 768; }
    else if (bid < 1536) { src = wo;   dst = dwo;             K = 1024; M = 512;  Kpad = 1024; local = bid - 1024; }
    else if (bid < 2944) { src = win;  dst = dwin;            K = 512;  M = 2730; Kpad = 512;  local = bid - 1536; interleave = 1; }
    else                 { src = wout; dst = dwout;           K = 1365; M = 512;  Kpad = 1408; local = bid - 2944; }
    int tilesx = Kpad >> 5;
    int k0 = (local % tilesx) * 32, m0 = (local / tilesx) * 32;
    int tx = threadIdx.x & 31, ty = threadIdx.x >> 5;
    #pragma unroll
    for (int i = 0; i < 4; ++i) {
        int k = k0 + ty + 8 * i, m = m0 + tx;
        tile[ty + 8 * i][tx] = (k < K && m < M) ? src[(size_t)k * M + m] : 0.f;
    }
    __syncthreads();
    #pragma unroll
    for (int i = 0; i < 4; ++i) {
        int n = m0 + ty + 8 * i, k = k0 + tx;
        int nd = n;
        if (interleave) nd = (n < DII) ? 2 * n : ((n < DI2) ? 2 * (n - DII) + 1 : n);
        dst[(size_t)nd * Kpad + k] = __float2bfloat16(tile[tx][ty + 8 * i]);
    }
}

// ---------------- RMSNorm (optional permuted read (b,t,s)->(b,s,t)) ----------------
template<int BF16OUT>
__global__ void rms_kernel(const float* __restrict__ x, const float* __restrict__ w,
                           void* __restrict__ out, int perm) {
    int r = blockIdx.x;
    int src = r;
    if (perm) {
        int t = r & 15; int rs = r >> 4; int s = rs % SSQ; int b = rs / SSQ;
        src = (b * TT + t) * SSQ + s;
    }
    const float* xr = x + (size_t)src * DIMD;
    int tid = threadIdx.x;
    float v0 = xr[tid], v1 = xr[tid + 256];
    __shared__ float red[256];
    red[tid] = v0 * v0 + v1 * v1;
    __syncthreads();
    for (int st = 128; st; st >>= 1) {
        if (tid < st) red[tid] += red[tid + st];
        __syncthreads();
    }
    float sc = rsqrtf(red[0] * (1.f / DIMD) + EPSR);
    if (BF16OUT) {
        bf16* o = (bf16*)out + (size_t)r * DIMD;
        o[tid] = __float2bfloat16(v0 * sc * w[tid]);
        o[tid + 256] = __float2bfloat16(v1 * sc * w[tid + 256]);
    } else {
        float* o = (float*)out + (size_t)r * DIMD;
        o[tid] = v0 * sc * w[tid];
        o[tid + 256] = v1 * sc * w[tid + 256];
    }
}

// ---------------- MFMA bf16 GEMM: C[nrow,M] = A[nrow,K] @ Bt[M,K]^T ----------------
// 128x128 tile, BK=32, 4 waves (2x2 of 64x64). EPI: 1 = qkv out + fused
// l2norm/gamma/rotary; 2 = glu out (interleaved a/g cols, writes col/2);
// 3 = fp32 accumulate (+bias, optional PERM row scatter).
template<int EPI, int PERM>
__global__ __launch_bounds__(256)
void mfma_gemm(const bf16* __restrict__ A, int lda,
               const bf16* __restrict__ Bt, int ldb,
               const float* __restrict__ bias,
               void* __restrict__ C, int ldc, int Mstore,
               int nrow, int K,
               const float* __restrict__ qg, const float* __restrict__ kg, int rotary) {
    __shared__ __align__(16) short lds_a[128 * 32];
    __shared__ __align__(16) short lds_b[128 * 32];
    int tid = threadIdx.x;
    int wave = tid >> 6, lane = tid & 63;
    int quad = lane >> 4, l16 = lane & 15;
    int m0 = blockIdx.y * 128, n0 = blockIdx.x * 128;
    int wm = (wave & 1) * 64, wn = (wave >> 1) * 64;
    f32x4 zero4 = {0.f, 0.f, 0.f, 0.f};
    f32x4 acc[4][4];
    #pragma unroll
    for (int i = 0; i < 4; ++i)
        #pragma unroll
        for (int j = 0; j < 4; ++j) acc[i][j] = zero4;

    int ca0 = (wave * 2 + 0) * 64 + lane;
    int ca1 = (wave * 2 + 1) * 64 + lane;
    int am0 = ca0 >> 2, ak0 = (ca0 & 3) ^ (am0 & 3);
    int am1 = ca1 >> 2, ak1 = (ca1 & 3) ^ (am1 & 3);
    int ar0 = m0 + am0; if (ar0 >= nrow) ar0 = nrow - 1;
    int ar1 = m0 + am1; if (ar1 >= nrow) ar1 = nrow - 1;
    const short* Ap = (const short*)A;
    const short* Bp = (const short*)Bt;
    const short* ga0 = Ap + (size_t)ar0 * lda + ak0 * 8;
    const short* ga1 = Ap + (size_t)ar1 * lda + ak1 * 8;
    const short* gb0 = Bp + (size_t)(n0 + am0) * ldb + ak0 * 8;
    const short* gb1 = Bp + (size_t)(n0 + am1) * ldb + ak1 * 8;
    short* la0 = &lds_a[(wave * 2 + 0) * 64 * 8];
    short* la1 = &lds_a[(wave * 2 + 1) * 64 * 8];
    short* lb0 = &lds_b[(wave * 2 + 0) * 64 * 8];
    short* lb1 = &lds_b[(wave * 2 + 1) * 64 * 8];
    int sxa = quad ^ (l16 & 3);

    int nk = K >> 5;
    for (int kt = 0; kt < nk; ++kt) {
        int k0 = kt * 32;
        async16(ga0 + k0, la0);
        async16(ga1 + k0, la1);
        async16(gb0 + k0, lb0);
        async16(gb1 + k0, lb1);
        __syncthreads();
        short8 af[4], bfr[4];
        #pragma unroll
        for (int mi = 0; mi < 4; ++mi) {
            int ml = wm + mi * 16 + l16;
            af[mi] = *(const short8*)&lds_a[(ml * 4 + sxa) * 8];
        }
        #pragma unroll
        for (int nj = 0; nj < 4; ++nj) {
            int nl = wn + nj * 16 + l16;
            bfr[nj] = *(const short8*)&lds_b[(nl * 4 + sxa) * 8];
        }
        #pragma unroll
        for (int mi = 0; mi < 4; ++mi)
            #pragma unroll
            for (int nj = 0; nj < 4; ++nj)
                acc[mi][nj] = __builtin_amdgcn_mfma_f32_16x16x32_bf16(
                    af[mi], bfr[nj], acc[mi][nj], 0, 0, 0);
        __syncthreads();
    }

    if constexpr (EPI == 1) {
        // qkv output: cols wn..wn+63 = exactly one head.
        int head = (n0 + wn) >> 6;          // 0..15 q, 16..23 k, 24..31 v
        float gl0 = 0.f, gl1 = 0.f, gl2 = 0.f, gl3 = 0.f, inv0 = 0.f, inv1 = 0.f;
        if (head < 24) {
            const float* g = head < 16 ? qg + head * 64 : kg + (head - 16) * 64;
            gl0 = (g[l16] + 1.f) * 8.f;
            gl1 = (g[16 + l16] + 1.f) * 8.f;
            gl2 = (g[32 + l16] + 1.f) * 8.f;
            gl3 = (g[48 + l16] + 1.f) * 8.f;
            if (rotary) {
                inv0 = __expf(-(float)l16 * 0.28782313662425572f);        // ln(1e4)/32
                inv1 = __expf(-(float)(l16 + 16) * 0.28782313662425572f);
            }
        }
        #pragma unroll
        for (int mi = 0; mi < 4; ++mi) {
            #pragma unroll
            for (int e = 0; e < 4; ++e) {
                int row = m0 + wm + mi * 16 + quad * 4 + e;
                float v0 = acc[mi][0][e], v1 = acc[mi][1][e];
                float v2 = acc[mi][2][e], v3 = acc[mi][3][e];
                if (head < 24) {
                    float ss = v0 * v0 + v1 * v1 + v2 * v2 + v3 * v3;
                    ss += __shfl_xor(ss, 1); ss += __shfl_xor(ss, 2);
                    ss += __shfl_xor(ss, 4); ss += __shfl_xor(ss, 8);
                    float invn = 1.f / fmaxf(sqrtf(ss), 1e-12f);
                    v0 *= invn * gl0; v1 *= invn * gl1;
                    v2 *= invn * gl2; v3 *= invn * gl3;
                    if (rotary) {
                        float t = (float)(row & 15);
                        float a0 = t * inv0, a1 = t * inv1;
                        float c0 = __cosf(a0), s0 = __sinf(a0);
                        float c1 = __cosf(a1), s1 = __sinf(a1);
                        float n0v = v0 * c0 - v2 * s0;
                        float n1v = v1 * c1 - v3 * s1;
                        float n2v = v2 * c0 + v0 * s0;
                        float n3v = v3 * c1 + v1 * s1;
                        v0 = n0v; v1 = n1v; v2 = n2v; v3 = n3v;
                    }
                }
                if (row < nrow) {
                    bf16* p = (bf16*)C + (size_t)row * ldc + n0 + wn + l16;
                    p[0]  = __float2bfloat16(v0);
                    p[16] = __float2bfloat16(v1);
                    p[32] = __float2bfloat16(v2);
                    p[48] = __float2bfloat16(v3);
                }
            }
        }
    } else if constexpr (EPI == 2) {
        // interleaved a/g: even col = a, odd col = g; write glu at col/2.
        #pragma unroll
        for (int mi = 0; mi < 4; ++mi) {
            #pragma unroll
            for (int e = 0; e < 4; ++e) {
                int row = m0 + wm + mi * 16 + quad * 4 + e;
                #pragma unroll
                for (int nj = 0; nj < 4; ++nj) {
                    int col = n0 + wn + nj * 16 + l16;
                    int j = col >> 1;
                    float b = (j < DII) ? ((col & 1) ? bias[DII + j] : bias[j]) : 0.f;
                    float v = acc[mi][nj][e] + b;
                    float prt = __shfl_xor(v, 1);
                    if (!(l16 & 1) && row < nrow) {
                        float gv = prt;
                        float glu = v * 0.5f * gv * (1.f + erff(gv * 0.70710678118654752f));
                        ((bf16*)C)[(size_t)row * ldc + j] = __float2bfloat16(glu);
                    }
                }
            }
        }
    } else {
        #pragma unroll
        for (int mi = 0; mi < 4; ++mi) {
            #pragma unroll
            for (int e = 0; e < 4; ++e) {
                int row = m0 + wm + mi * 16 + quad * 4 + e;
                if (row >= nrow) continue;
                int orow = row;
                if (PERM) {
                    int t = row & 15; int rs = row >> 4; int s = rs % SSQ; int b = rs / SSQ;
                    orow = (b * TT + t) * SSQ + s;
                }
                #pragma unroll
                for (int nj = 0; nj < 4; ++nj) {
                    int col = n0 + wn + nj * 16 + l16;
                    if (col >= Mstore) continue;
                    float v = acc[mi][nj][e];
                    if (bias) v += bias[col];
                    ((float*)C)[(size_t)orow * ldc + col] += v;
                }
            }
        }
    }
}

// ---------------- V transpose for PV MFMA: vt[bt*8+kh][64][SKP] bf16 ----------------
__global__ void vtrans_kernel(const bf16* __restrict__ qkv, bf16* __restrict__ vt) {
    int bkh = blockIdx.x;          // bt*8 + kh
    int kc = blockIdx.y;           // key chunk of 32
    int bt = bkh >> 3, kh = bkh & 7;
    int tid = threadIdx.x;
    #pragma unroll
    for (int i = 0; i < 8; ++i) {
        int idx = tid + 256 * i;   // 0..2047
        int kl = idx >> 6;         // key local
        int d = idx & 63;
        int key = kc * 32 + kl;
        float v = 0.f;
        if (key < SSQ)
            v = __bfloat162float(qkv[((size_t)(bt * SSQ + key)) * 2048 + 1536 + kh * 64 + d]);
        vt[((size_t)bkh * 64 + d) * SKP + key] = __float2bfloat16(v);
    }
}

// ---------------- space attention: 4 waves per 32-q tile ----------------
// grid (9, 16, 32) = (q32-tile, qh, bt); block 256.
// QK^T: waves stripe the 18 key16-tiles. softmax: 8 lanes/row. PV: waves
// stripe the 4 d16-tiles.
__global__ __launch_bounds__(256)
void space_attn_kernel(const bf16* __restrict__ qkv, const bf16* __restrict__ vt,
                       bf16* __restrict__ ob) {
    __shared__ __align__(16) float scores[32][292];
    __shared__ float rowinv[32];
    int qt = blockIdx.x, qh = blockIdx.y, bt = blockIdx.z;
    int kh = qh >> 1;
    int tid = threadIdx.x, wave = tid >> 6, lane = tid & 63;
    int quad = lane >> 4, l16 = lane & 15;
    int q0 = qt * 32;
    const short* qbase = (const short*)qkv + (size_t)bt * SSQ * 2048;
    f32x4 zero4 = {0.f, 0.f, 0.f, 0.f};
    short8 a[2][2];
    #pragma unroll
    for (int m = 0; m < 2; ++m) {
        int qi = q0 + m * 16 + l16; if (qi > 256) qi = 256;
        const short* qp = qbase + (size_t)qi * 2048 + qh * 64;
        a[m][0] = *(const short8*)(qp + quad * 8);
        a[m][1] = *(const short8*)(qp + 32 + quad * 8);
    }
    for (int kt = wave; kt < 18; kt += 4) {
        int key = kt * 16 + l16; int keyc = key > 256 ? 256 : key;
        const short* kp = qbase + (size_t)keyc * 2048 + 1024 + kh * 64;
        short8 b0 = *(const short8*)(kp + quad * 8);
        short8 b1 = *(const short8*)(kp + 32 + quad * 8);
        #pragma unroll
        for (int m = 0; m < 2; ++m) {
            f32x4 c = zero4;
            c = __builtin_amdgcn_mfma_f32_16x16x32_bf16(a[m][0], b0, c, 0, 0, 0);
            c = __builtin_amdgcn_mfma_f32_16x16x32_bf16(a[m][1], b1, c, 0, 0, 0);
            #pragma unroll
            for (int e = 0; e < 4; ++e) {
                int ql = m * 16 + quad * 4 + e;
                int qq = q0 + ql;
                int j = kt * 16 + l16;
                float s = c[e] * 0.125f;
                float ex = __expf(s * 0.04f);            // tanh(s/50)*50 softclamp
                s = 50.f * (ex - 1.f) / (ex + 1.f);
                if (j > 256 || (qq < 256 && j == 256)) s = -1e30f;
                int cs = (j & ~31) | ((((j >> 3) & 3) ^ (ql & 3)) << 3) | (j & 7);
                scores[ql][cs] = s;
            }
        }
    }
    __syncthreads();
    {   // softmax: 32 rows, 8 lanes per row, 36 cols each
        int r = tid >> 3, p8 = tid & 7;
        float mx = -1e30f;
        #pragma unroll 4
        for (int t = 0; t < 36; ++t) mx = fmaxf(mx, scores[r][p8 + 8 * t]);
        mx = fmaxf(mx, __shfl_xor(mx, 1));
        mx = fmaxf(mx, __shfl_xor(mx, 2));
        mx = fmaxf(mx, __shfl_xor(mx, 4));
        float sum = 0.f;
        #pragma unroll 4
        for (int t = 0; t < 36; ++t) {
            float p = __expf(scores[r][p8 + 8 * t] - mx);
            scores[r][p8 + 8 * t] = p;
            sum += p;
        }
        sum += __shfl_xor(sum, 1);
        sum += __shfl_xor(sum, 2);
        sum += __shfl_xor(sum, 4);
        if (p8 == 0) rowinv[r] = 1.f / sum;
    }
    __syncthreads();
    // PV: wave handles d-tile nt = wave
    int nt = wave;
    const short* vbp = (const short*)vt + ((size_t)(bt * 8 + kh) * 64 + nt * 16 + l16) * SKP;
    #pragma unroll
    for (int m = 0; m < 2; ++m) {
        f32x4 oacc = zero4;
        int ql = m * 16 + l16;
        int cc = (quad ^ (ql & 3)) * 8;
        for (int kc = 0; kc < 9; ++kc) {
            const float* prow = &scores[ql][kc * 32 + cc];
            f32x4 p0 = *(const f32x4*)prow;
            f32x4 p1 = *(const f32x4*)(prow + 4);
            short8 af;
            #pragma unroll
            for (int j = 0; j < 4; ++j) { af[j] = f2bfs(p0[j]); af[4 + j] = f2bfs(p1[j]); }
            short8 bv = *(const short8*)(vbp + kc * 32 + quad * 8);
            oacc = __builtin_amdgcn_mfma_f32_16x16x32_bf16(af, bv, oacc, 0, 0, 0);
        }
        #pragma unroll
        for (int e = 0; e < 4; ++e) {
            int qq = q0 + m * 16 + quad * 4 + e;
            if (qq <= 256) {
                float inv = rowinv[m * 16 + quad * 4 + e];
                ob[((size_t)(bt * SSQ + qq)) * 1024 + qh * 64 + nt * 16 + l16] =
                    __float2bfloat16(oacc[e] * inv);
            }
        }
    }
}

// ---------------- time attention (n=16, causal): one block per (b*s, qh) ----------------
__global__ void time_attn_kernel(const bf16* __restrict__ qkv, bf16* __restrict__ ob) {
    __shared__ float qs[16][65], ks[16][65], ps[16][17];
    int bs = blockIdx.x, qh = blockIdx.y, kh = qh >> 1;
    int tid = threadIdx.x;
    size_t rowbase = (size_t)bs * 16;
    #pragma unroll
    for (int i = 0; i < 4; ++i) {
        int idx = tid + 256 * i;
        int r = idx >> 6, d = idx & 63;
        qs[r][d] = __bfloat162float(qkv[(rowbase + r) * 2048 + qh * 64 + d]);
        ks[r][d] = __bfloat162float(qkv[(rowbase + r) * 2048 + 1024 + kh * 64 + d]);
    }
    __syncthreads();
    int i = tid >> 4, j = tid & 15;
    float dot = 0.f;
    #pragma unroll 16
    for (int d = 0; d < 64; ++d) dot += qs[i][d] * ks[j][d];
    float s = dot * 0.125f;
    float ex = __expf(s * 0.04f);
    s = 50.f * (ex - 1.f) / (ex + 1.f);
    if (j > i) s = -1e30f;
    float mx = s;
    mx = fmaxf(mx, __shfl_xor(mx, 1));
    mx = fmaxf(mx, __shfl_xor(mx, 2));
    mx = fmaxf(mx, __shfl_xor(mx, 4));
    mx = fmaxf(mx, __shfl_xor(mx, 8));
    float p = __expf(s - mx);
    float sum = p;
    sum += __shfl_xor(sum, 1);
    sum += __shfl_xor(sum, 2);
    sum += __shfl_xor(sum, 4);
    sum += __shfl_xor(sum, 8);
    ps[i][j] = p / sum;
    __syncthreads();
    #pragma unroll
    for (int ii = 0; ii < 4; ++ii) {
        int idx = tid + 256 * ii;
        int r = idx >> 6, d = idx & 63;
        float acc = 0.f;
        #pragma unroll
        for (int jj = 0; jj < 16; ++jj)
            acc += ps[r][jj] * __bfloat162float(qkv[(rowbase + jj) * 2048 + 1536 + kh * 64 + d]);
        ob[(rowbase + r) * 1024 + qh * 64 + d] = __float2bfloat16(acc);
    }
}

// ---------------- host-side launch ----------------
extern "C" void kernel_launch(void* const* d_in, const int* in_sizes, int n_in,
                              void* d_out, int out_size, void* d_ws, size_t ws_size,
                              hipStream_t stream) {
    const float* tokens      = (const float*)d_in[0];
    const float* attn_norm_w = (const float*)d_in[1];
    const float* Wq          = (const float*)d_in[2];
    const float* Wk          = (const float*)d_in[3];
    const float* Wv          = (const float*)d_in[4];
    const float* q_gamma     = (const float*)d_in[5];
    const float* k_gamma     = (const float*)d_in[6];
    const float* Wo          = (const float*)d_in[7];
    const float* ff_norm_w   = (const float*)d_in[8];
    const float* W_in        = (const float*)d_in[9];
    const float* b_in        = (const float*)d_in[10];
    const float* W_out       = (const float*)d_in[11];
    const float* b_out       = (const float*)d_in[12];
    const float* final_w     = (const float*)d_in[13];

    float* x = (float*)d_out;
    char* ws = (char*)d_ws;

    // per-layer bf16 weight slab (reused each layer)
    bf16* wtqkv = (bf16*)ws;                     // [2048][512]
    bf16* wto   = wtqkv + 2048 * 512;            // [512][1024]
    bf16* wtin  = wto   + 512 * 1024;            // [2816][512] interleaved
    bf16* wtout = wtin  + 2816 * 512;            // [512][1408]
    size_t off = (size_t)(2048*512 + 512*1024 + 2816*512 + 512*1408) * 2;  // 7,471,104
    bf16* h = (bf16*)(ws + off);                 // [N][512]
    off += (size_t)NROWS * 512 * 2;
    char* region = ws + off;
    bf16* qkv = (bf16*)region;                               // [N][2048]  33.7 MB
    bf16* glu = (bf16*)region;                               // [N][1408]  (FF phase alias)
    bf16* vt  = (bf16*)(region + (size_t)NROWS * 2048 * 2);  // [256][64][288]  9.4 MB
    bf16* ob  = (bf16*)(region + (size_t)NROWS * 2048 * 2 + (size_t)256*64*SKP*2);  // [N][1024]

    hipMemcpyAsync(x, tokens, (size_t)NROWS * 512 * 4, hipMemcpyDeviceToDevice, stream);

    for (int l = 0; l < 8; ++l) {
        int is_time = ((l + 1) % 4 == 0) ? 1 : 0;
        wtrans_layer<<<3648, 256, 0, stream>>>(
            Wq + (size_t)l * 512 * 1024, Wk + (size_t)l * 512 * 512,
            Wv + (size_t)l * 512 * 512, Wo + (size_t)l * 1024 * 512,
            W_in + (size_t)l * 512 * DI2, W_out + (size_t)l * DII * 512,
            wtqkv, wto, wtin, wtout);

        // ---- attention block ----
        rms_kernel<1><<<NROWS, 256, 0, stream>>>(x, attn_norm_w + (size_t)l * 512, h, is_time);
        mfma_gemm<1, 0><<<dim3(16, 65), 256, 0, stream>>>(
            h, 512, wtqkv, 512, nullptr, qkv, 2048, 2048, NROWS, 512,
            q_gamma + (size_t)l * 1024, k_gamma + (size_t)l * 512, is_time);
        if (is_time) {
            time_attn_kernel<<<dim3(514, 16), 256, 0, stream>>>(qkv, ob);
            mfma_gemm<3, 1><<<dim3(4, 65), 256, 0, stream>>>(
                ob, 1024, wto, 1024, nullptr, x, 512, 512, NROWS, 1024, nullptr, nullptr, 0);
        } else {
            vtrans_kernel<<<dim3(256, 9), 256, 0, stream>>>(qkv, vt);
            space_attn_kernel<<<dim3(9, 16, 32), 256, 0, stream>>>(qkv, vt, ob);
            mfma_gemm<3, 0><<<dim3(4, 65), 256, 0, stream>>>(
                ob, 1024, wto, 1024, nullptr, x, 512, 512, NROWS, 1024, nullptr, nullptr, 0);
        }

        // ---- feed-forward block ----
        rms_kernel<1><<<NROWS, 256, 0, stream>>>(x, ff_norm_w + (size_t)l * 512, h, 0);
        mfma_gemm<2, 0><<<dim3(22, 65), 256, 0, stream>>>(
            h, 512, wtin, 512, b_in + (size_t)l * DI2, glu, GLULD, FNPAD, NROWS, 512,
            nullptr, nullptr, 0);
        mfma_gemm<3, 0><<<dim3(4, 65), 256, 0, stream>>>(
            glu, GLULD, wtout, GLULD, b_out + (size_t)l * 512, x, 512, 512, NROWS, GLULD,
            nullptr, nullptr, 0);
    }

    rms_kernel<0><<<NROWS, 256, 0, stream>>>(x, final_w, x, 0);
}

// Round 4
// 2772.830 us; speedup vs baseline: 8.0377x; 1.0302x over previous
//
#include <hip/hip_runtime.h>
#include <hip/hip_bf16.h>
#include <math.h>

typedef __attribute__((ext_vector_type(8))) short short8;
typedef __attribute__((ext_vector_type(4))) float f32x4;
typedef __hip_bfloat16 bf16;

#define BB 2
#define TT 16
#define SSQ 257
#define DIMD 512
#define NROWS 8224          // B*T*S
#define DII 1365
#define DI2 2730
#define FNPAD 2816          // ff_in N padded (22*128), interleaved a/g pairs
#define GLULD 1408          // glu row stride / ff_out K (44*32)
#define SKP 288             // padded key count for space attn
#define EPSR 1.1920929e-07f

__device__ __forceinline__ void async16(const void* g, const void* l) {
    __builtin_amdgcn_global_load_lds(
        (const __attribute__((address_space(1))) void*)g,
        (__attribute__((address_space(3))) void*)l, 16, 0, 0);
}

__device__ __forceinline__ short f2bfs(float x) {
    bf16 h = __float2bfloat16(x);
    return *reinterpret_cast<short*>(&h);
}

// ---------------- batched per-layer weight transpose fp32->bf16 ----------------
// Segments (flattened 32x32 tiles): Wq 512 | Wk 256 | Wv 256 | Wo 512 | Win 1408
// (column-interleaved a/g) | Wout 704  => grid 3648, block 256.
__global__ void wtrans_layer(const float* __restrict__ wq, const float* __restrict__ wk,
                             const float* __restrict__ wv, const float* __restrict__ wo,
                             const float* __restrict__ win, const float* __restrict__ wout,
                             bf16* __restrict__ dqkv, bf16* __restrict__ dwo,
                             bf16* __restrict__ dwin, bf16* __restrict__ dwout) {
    __shared__ float tile[32][33];
    int bid = blockIdx.x;
    const float* src; bf16* dst; int K, M, Kpad, interleave = 0, local;
    if (bid < 512)       { src = wq;   dst = dqkv;            K = 512;  M = 1024; Kpad = 512;  local = bid; }
    else if (bid < 768)  { src = wk;   dst = dqkv + 1024*512; K = 512;  M = 512;  Kpad = 512;  local = bid - 512; }
    else if (bid < 1024) { src = wv;   dst = dqkv + 1536*512; K = 512;  M = 512;  Kpad = 512;  local = bid - 768; }
    else if (bid < 1536) { src = wo;   dst = dwo;             K = 1024; M = 512;  Kpad = 1024; local = bid - 1024; }
    else if (bid < 2944) { src = win;  dst = dwin;            K = 512;  M = 2730; Kpad = 512;  local = bid - 1536; interleave = 1; }
    else                 { src = wout; dst = dwout;           K = 1365; M = 512;  Kpad = 1408; local = bid - 2944; }
    int tilesx = Kpad >> 5;
    int k0 = (local % tilesx) * 32, m0 = (local / tilesx) * 32;
    int tx = threadIdx.x & 31, ty = threadIdx.x >> 5;
    #pragma unroll
    for (int i = 0; i < 4; ++i) {
        int k = k0 + ty + 8 * i, m = m0 + tx;
        tile[ty + 8 * i][tx] = (k < K && m < M) ? src[(size_t)k * M + m] : 0.f;
    }
    __syncthreads();
    #pragma unroll
    for (int i = 0; i < 4; ++i) {
        int n = m0 + ty + 8 * i, k = k0 + tx;
        int nd = n;
        if (interleave) nd = (n < DII) ? 2 * n : ((n < DI2) ? 2 * (n - DII) + 1 : n);
        dst[(size_t)nd * Kpad + k] = __float2bfloat16(tile[tx][ty + 8 * i]);
    }
}

// ---------------- RMSNorm (optional permuted read (b,t,s)->(b,s,t)) ----------------
template<int BF16OUT>
__global__ void rms_kernel(const float* __restrict__ x, const float* __restrict__ w,
                           void* __restrict__ out, int perm) {
    int r = blockIdx.x;
    int src = r;
    if (perm) {
        int t = r & 15; int rs = r >> 4; int s = rs % SSQ; int b = rs / SSQ;
        src = (b * TT + t) * SSQ + s;
    }
    const float* xr = x + (size_t)src * DIMD;
    int tid = threadIdx.x;
    float v0 = xr[tid], v1 = xr[tid + 256];
    __shared__ float red[256];
    red[tid] = v0 * v0 + v1 * v1;
    __syncthreads();
    for (int st = 128; st; st >>= 1) {
        if (tid < st) red[tid] += red[tid + st];
        __syncthreads();
    }
    float sc = rsqrtf(red[0] * (1.f / DIMD) + EPSR);
    if (BF16OUT) {
        bf16* o = (bf16*)out + (size_t)r * DIMD;
        o[tid] = __float2bfloat16(v0 * sc * w[tid]);
        o[tid + 256] = __float2bfloat16(v1 * sc * w[tid + 256]);
    } else {
        float* o = (float*)out + (size_t)r * DIMD;
        o[tid] = v0 * sc * w[tid];
        o[tid + 256] = v1 * sc * w[tid + 256];
    }
}

// ---------------- MFMA bf16 GEMM: C[nrow,M] = A[nrow,K] @ Bt[M,K]^T ----------------
// 128x128 tile, BK=32, 4 waves (2x2 of 64x64). EPI: 1 = qkv out + fused
// l2norm/gamma/rotary; 2 = glu out (interleaved a/g cols, writes col/2);
// 3 = fp32 accumulate (+bias, optional PERM row scatter).
template<int EPI, int PERM>
__global__ __launch_bounds__(256)
void mfma_gemm(const bf16* __restrict__ A, int lda,
               const bf16* __restrict__ Bt, int ldb,
               const float* __restrict__ bias,
               void* __restrict__ C, int ldc, int Mstore,
               int nrow, int K,
               const float* __restrict__ qg, const float* __restrict__ kg, int rotary) {
    __shared__ __align__(16) short lds_a[128 * 32];
    __shared__ __align__(16) short lds_b[128 * 32];
    int tid = threadIdx.x;
    int wave = tid >> 6, lane = tid & 63;
    int quad = lane >> 4, l16 = lane & 15;
    int m0 = blockIdx.y * 128, n0 = blockIdx.x * 128;
    int wm = (wave & 1) * 64, wn = (wave >> 1) * 64;
    f32x4 zero4 = {0.f, 0.f, 0.f, 0.f};
    f32x4 acc[4][4];
    #pragma unroll
    for (int i = 0; i < 4; ++i)
        #pragma unroll
        for (int j = 0; j < 4; ++j) acc[i][j] = zero4;

    int ca0 = (wave * 2 + 0) * 64 + lane;
    int ca1 = (wave * 2 + 1) * 64 + lane;
    int am0 = ca0 >> 2, ak0 = (ca0 & 3) ^ (am0 & 3);
    int am1 = ca1 >> 2, ak1 = (ca1 & 3) ^ (am1 & 3);
    int ar0 = m0 + am0; if (ar0 >= nrow) ar0 = nrow - 1;
    int ar1 = m0 + am1; if (ar1 >= nrow) ar1 = nrow - 1;
    const short* Ap = (const short*)A;
    const short* Bp = (const short*)Bt;
    const short* ga0 = Ap + (size_t)ar0 * lda + ak0 * 8;
    const short* ga1 = Ap + (size_t)ar1 * lda + ak1 * 8;
    const short* gb0 = Bp + (size_t)(n0 + am0) * ldb + ak0 * 8;
    const short* gb1 = Bp + (size_t)(n0 + am1) * ldb + ak1 * 8;
    short* la0 = &lds_a[(wave * 2 + 0) * 64 * 8];
    short* la1 = &lds_a[(wave * 2 + 1) * 64 * 8];
    short* lb0 = &lds_b[(wave * 2 + 0) * 64 * 8];
    short* lb1 = &lds_b[(wave * 2 + 1) * 64 * 8];
    int sxa = quad ^ (l16 & 3);

    int nk = K >> 5;
    for (int kt = 0; kt < nk; ++kt) {
        int k0 = kt * 32;
        async16(ga0 + k0, la0);
        async16(ga1 + k0, la1);
        async16(gb0 + k0, lb0);
        async16(gb1 + k0, lb1);
        __syncthreads();
        short8 af[4], bfr[4];
        #pragma unroll
        for (int mi = 0; mi < 4; ++mi) {
            int ml = wm + mi * 16 + l16;
            af[mi] = *(const short8*)&lds_a[(ml * 4 + sxa) * 8];
        }
        #pragma unroll
        for (int nj = 0; nj < 4; ++nj) {
            int nl = wn + nj * 16 + l16;
            bfr[nj] = *(const short8*)&lds_b[(nl * 4 + sxa) * 8];
        }
        #pragma unroll
        for (int mi = 0; mi < 4; ++mi)
            #pragma unroll
            for (int nj = 0; nj < 4; ++nj)
                acc[mi][nj] = __builtin_amdgcn_mfma_f32_16x16x32_bf16(
                    af[mi], bfr[nj], acc[mi][nj], 0, 0, 0);
        __syncthreads();
    }

    if constexpr (EPI == 1) {
        // qkv output: cols wn..wn+63 = exactly one head.
        int head = (n0 + wn) >> 6;          // 0..15 q, 16..23 k, 24..31 v
        float gl0 = 0.f, gl1 = 0.f, gl2 = 0.f, gl3 = 0.f, inv0 = 0.f, inv1 = 0.f;
        if (head < 24) {
            const float* g = head < 16 ? qg + head * 64 : kg + (head - 16) * 64;
            gl0 = (g[l16] + 1.f) * 8.f;
            gl1 = (g[16 + l16] + 1.f) * 8.f;
            gl2 = (g[32 + l16] + 1.f) * 8.f;
            gl3 = (g[48 + l16] + 1.f) * 8.f;
            if (rotary) {
                inv0 = __expf(-(float)l16 * 0.28782313662425572f);        // ln(1e4)/32
                inv1 = __expf(-(float)(l16 + 16) * 0.28782313662425572f);
            }
        }
        #pragma unroll
        for (int mi = 0; mi < 4; ++mi) {
            #pragma unroll
            for (int e = 0; e < 4; ++e) {
                int row = m0 + wm + mi * 16 + quad * 4 + e;
                float v0 = acc[mi][0][e], v1 = acc[mi][1][e];
                float v2 = acc[mi][2][e], v3 = acc[mi][3][e];
                if (head < 24) {
                    float ss = v0 * v0 + v1 * v1 + v2 * v2 + v3 * v3;
                    ss += __shfl_xor(ss, 1); ss += __shfl_xor(ss, 2);
                    ss += __shfl_xor(ss, 4); ss += __shfl_xor(ss, 8);
                    float invn = 1.f / fmaxf(sqrtf(ss), 1e-12f);
                    v0 *= invn * gl0; v1 *= invn * gl1;
                    v2 *= invn * gl2; v3 *= invn * gl3;
                    if (rotary) {
                        float t = (float)(row & 15);
                        float a0 = t * inv0, a1 = t * inv1;
                        float c0 = __cosf(a0), s0 = __sinf(a0);
                        float c1 = __cosf(a1), s1 = __sinf(a1);
                        float n0v = v0 * c0 - v2 * s0;
                        float n1v = v1 * c1 - v3 * s1;
                        float n2v = v2 * c0 + v0 * s0;
                        float n3v = v3 * c1 + v1 * s1;
                        v0 = n0v; v1 = n1v; v2 = n2v; v3 = n3v;
                    }
                }
                if (row < nrow) {
                    bf16* p = (bf16*)C + (size_t)row * ldc + n0 + wn + l16;
                    p[0]  = __float2bfloat16(v0);
                    p[16] = __float2bfloat16(v1);
                    p[32] = __float2bfloat16(v2);
                    p[48] = __float2bfloat16(v3);
                }
            }
        }
    } else if constexpr (EPI == 2) {
        // interleaved a/g: even col = a, odd col = g; write glu at col/2.
        #pragma unroll
        for (int mi = 0; mi < 4; ++mi) {
            #pragma unroll
            for (int e = 0; e < 4; ++e) {
                int row = m0 + wm + mi * 16 + quad * 4 + e;
                #pragma unroll
                for (int nj = 0; nj < 4; ++nj) {
                    int col = n0 + wn + nj * 16 + l16;
                    int j = col >> 1;
                    float b = (j < DII) ? ((col & 1) ? bias[DII + j] : bias[j]) : 0.f;
                    float v = acc[mi][nj][e] + b;
                    float prt = __shfl_xor(v, 1);
                    if (!(l16 & 1) && row < nrow) {
                        float gv = prt;
                        float glu = v * 0.5f * gv * (1.f + erff(gv * 0.70710678118654752f));
                        ((bf16*)C)[(size_t)row * ldc + j] = __float2bfloat16(glu);
                    }
                }
            }
        }
    } else {
        #pragma unroll
        for (int mi = 0; mi < 4; ++mi) {
            #pragma unroll
            for (int e = 0; e < 4; ++e) {
                int row = m0 + wm + mi * 16 + quad * 4 + e;
                if (row >= nrow) continue;
                int orow = row;
                if (PERM) {
                    int t = row & 15; int rs = row >> 4; int s = rs % SSQ; int b = rs / SSQ;
                    orow = (b * TT + t) * SSQ + s;
                }
                #pragma unroll
                for (int nj = 0; nj < 4; ++nj) {
                    int col = n0 + wn + nj * 16 + l16;
                    if (col >= Mstore) continue;
                    float v = acc[mi][nj][e];
                    if (bias) v += bias[col];
                    ((float*)C)[(size_t)orow * ldc + col] += v;
                }
            }
        }
    }
}

// ---------------- V transpose for PV MFMA: vt[bt*8+kh][64][SKP] bf16 ----------------
__global__ void vtrans_kernel(const bf16* __restrict__ qkv, bf16* __restrict__ vt) {
    int bkh = blockIdx.x;          // bt*8 + kh
    int kc = blockIdx.y;           // key chunk of 32
    int bt = bkh >> 3, kh = bkh & 7;
    int tid = threadIdx.x;
    #pragma unroll
    for (int i = 0; i < 8; ++i) {
        int idx = tid + 256 * i;   // 0..2047
        int kl = idx >> 6;         // key local
        int d = idx & 63;
        int key = kc * 32 + kl;
        float v = 0.f;
        if (key < SSQ)
            v = __bfloat162float(qkv[((size_t)(bt * SSQ + key)) * 2048 + 1536 + kh * 64 + d]);
        vt[((size_t)bkh * 64 + d) * SKP + key] = __float2bfloat16(v);
    }
}

// ---------------- space attention: S^T in registers, zero LDS ----------------
// grid (5, 16, 32) = (q64-tile, qh, bt); block 256 (4 waves, 16 q-rows each).
// Each wave: S^T = K.Q^T (key in regs, q in lanes) -> softmax per-lane ->
// P chunks via shfl gather -> O = P.V with C-layout [q=reg][d=lane].
__global__ __launch_bounds__(256)
void space_attn_kernel(const bf16* __restrict__ qkv, const bf16* __restrict__ vt,
                       bf16* __restrict__ ob) {
    int qt = blockIdx.x, qh = blockIdx.y, bt = blockIdx.z;
    int kh = qh >> 1;
    int tid = threadIdx.x, wave = tid >> 6, lane = tid & 63;
    int quad = lane >> 4, l16 = lane & 15;
    int q0w = qt * 64 + wave * 16;
    int q = q0w + l16;                     // this lane's q column
    int qc = q > 256 ? 256 : q;
    const short* qbase = (const short*)qkv + (size_t)bt * SSQ * 2048;
    // B operand: Q rows (n = l16 = q, k = quad*8+j = d)
    const short* qp = qbase + (size_t)qc * 2048 + qh * 64;
    short8 bq0 = *(const short8*)(qp + quad * 8);
    short8 bq1 = *(const short8*)(qp + 32 + quad * 8);
    f32x4 zero4 = {0.f, 0.f, 0.f, 0.f};
    f32x4 sc[18];

    // ---- S^T: 17 key-tiles of 16 (keys 0..271; 272..287 fully masked) ----
    #pragma unroll
    for (int kt = 0; kt < 17; ++kt) {
        int keyl = kt * 16 + l16; if (keyl > 256) keyl = 256;   // A row load (m=l16=key)
        const short* kp = qbase + (size_t)keyl * 2048 + 1024 + kh * 64;
        short8 ak0 = *(const short8*)(kp + quad * 8);
        short8 ak1 = *(const short8*)(kp + 32 + quad * 8);
        f32x4 c = zero4;
        c = __builtin_amdgcn_mfma_f32_16x16x32_bf16(ak0, bq0, c, 0, 0, 0);
        c = __builtin_amdgcn_mfma_f32_16x16x32_bf16(ak1, bq1, c, 0, 0, 0);
        #pragma unroll
        for (int e = 0; e < 4; ++e) {
            // softclamp: 50*tanh(dot*0.125/50) = 50 - 100/(exp(dot*0.005)+1)
            float e2x = __expf(c[e] * 0.005f);
            float v = 50.f - 100.f * __builtin_amdgcn_rcpf(e2x + 1.f);
            if (kt == 16) {
                // keys 256..271: only key==256 (quad==0,e==0) valid, and only for q==256
                bool valid = (e == 0) && (quad == 0) && (q == 256);
                v = valid ? v : -1e30f;
            }
            c[e] = v;
        }
        sc[kt] = c;
    }

    // ---- softmax over keys: e-wise regs + cross-quad shfl ----
    float mx = -1e30f;
    #pragma unroll
    for (int kt = 0; kt < 17; ++kt)
        mx = fmaxf(mx, fmaxf(fmaxf(sc[kt][0], sc[kt][1]), fmaxf(sc[kt][2], sc[kt][3])));
    mx = fmaxf(mx, __shfl_xor(mx, 16));
    mx = fmaxf(mx, __shfl_xor(mx, 32));
    float sum = 0.f;
    #pragma unroll
    for (int kt = 0; kt < 17; ++kt) {
        #pragma unroll
        for (int e = 0; e < 4; ++e) {
            float p = __expf(sc[kt][e] - mx);
            sc[kt][e] = p;
            sum += p;
        }
    }
    #pragma unroll
    for (int e = 0; e < 4; ++e) sc[17][e] = 0.f;
    sum += __shfl_xor(sum, 16);
    sum += __shfl_xor(sum, 32);
    float inv = __builtin_amdgcn_rcpf(sum);
    // inv per q-row for the O epilogue (q = quad*4+e there)
    f32x4 inv4;
    #pragma unroll
    for (int e = 0; e < 4; ++e) inv4[e] = __shfl(inv, quad * 4 + e);

    // ---- O = P.V : A = P (m=l16=q, k=key), B = V^T rows (n=l16=d, k=key) ----
    f32x4 oacc[4];
    #pragma unroll
    for (int nt = 0; nt < 4; ++nt) oacc[nt] = zero4;
    const short* vbp = (const short*)vt + ((size_t)(bt * 8 + kh) * 64 + l16) * SKP;
    #pragma unroll
    for (int c8 = 0; c8 < 9; ++c8) {
        short8 pb;
        #pragma unroll
        for (int j = 0; j < 8; ++j) {
            int src_lane = ((quad & 1) * 2 + (j >> 2)) * 16 + l16;
            float v0 = __shfl(sc[2 * c8][j & 3], src_lane);
            float v1 = __shfl(sc[2 * c8 + 1][j & 3], src_lane);
            pb[j] = f2bfs(quad < 2 ? v0 : v1);
        }
        #pragma unroll
        for (int nt = 0; nt < 4; ++nt) {
            short8 av = *(const short8*)(vbp + (size_t)(nt * 16) * SKP + c8 * 32 + quad * 8);
            oacc[nt] = __builtin_amdgcn_mfma_f32_16x16x32_bf16(pb, av, oacc[nt], 0, 0, 0);
        }
    }

    // ---- store: O[q=q0w+quad*4+e][d=nt*16+l16] ----
    #pragma unroll
    for (int e = 0; e < 4; ++e) {
        int qq = q0w + quad * 4 + e;
        if (qq <= 256) {
            bf16* op = ob + ((size_t)(bt * SSQ + qq)) * 1024 + qh * 64 + l16;
            float s = inv4[e];
            op[0]  = __float2bfloat16(oacc[0][e] * s);
            op[16] = __float2bfloat16(oacc[1][e] * s);
            op[32] = __float2bfloat16(oacc[2][e] * s);
            op[48] = __float2bfloat16(oacc[3][e] * s);
        }
    }
}

// ---------------- time attention (n=16, causal): one block per (b*s, qh) ----------------
__global__ void time_attn_kernel(const bf16* __restrict__ qkv, bf16* __restrict__ ob) {
    __shared__ float qs[16][65], ks[16][65], ps[16][17];
    int bs = blockIdx.x, qh = blockIdx.y, kh = qh >> 1;
    int tid = threadIdx.x;
    size_t rowbase = (size_t)bs * 16;
    #pragma unroll
    for (int i = 0; i < 4; ++i) {
        int idx = tid + 256 * i;
        int r = idx >> 6, d = idx & 63;
        qs[r][d] = __bfloat162float(qkv[(rowbase + r) * 2048 + qh * 64 + d]);
        ks[r][d] = __bfloat162float(qkv[(rowbase + r) * 2048 + 1024 + kh * 64 + d]);
    }
    __syncthreads();
    int i = tid >> 4, j = tid & 15;
    float dot = 0.f;
    #pragma unroll 16
    for (int d = 0; d < 64; ++d) dot += qs[i][d] * ks[j][d];
    float s = dot * 0.125f;
    float ex = __expf(s * 0.04f);
    s = 50.f * (ex - 1.f) / (ex + 1.f);
    if (j > i) s = -1e30f;
    float mx = s;
    mx = fmaxf(mx, __shfl_xor(mx, 1));
    mx = fmaxf(mx, __shfl_xor(mx, 2));
    mx = fmaxf(mx, __shfl_xor(mx, 4));
    mx = fmaxf(mx, __shfl_xor(mx, 8));
    float p = __expf(s - mx);
    float sum = p;
    sum += __shfl_xor(sum, 1);
    sum += __shfl_xor(sum, 2);
    sum += __shfl_xor(sum, 4);
    sum += __shfl_xor(sum, 8);
    ps[i][j] = p / sum;
    __syncthreads();
    #pragma unroll
    for (int ii = 0; ii < 4; ++ii) {
        int idx = tid + 256 * ii;
        int r = idx >> 6, d = idx & 63;
        float acc = 0.f;
        #pragma unroll
        for (int jj = 0; jj < 16; ++jj)
            acc += ps[r][jj] * __bfloat162float(qkv[(rowbase + jj) * 2048 + 1536 + kh * 64 + d]);
        ob[(rowbase + r) * 1024 + qh * 64 + d] = __float2bfloat16(acc);
    }
}

// ---------------- host-side launch ----------------
extern "C" void kernel_launch(void* const* d_in, const int* in_sizes, int n_in,
                              void* d_out, int out_size, void* d_ws, size_t ws_size,
                              hipStream_t stream) {
    const float* tokens      = (const float*)d_in[0];
    const float* attn_norm_w = (const float*)d_in[1];
    const float* Wq          = (const float*)d_in[2];
    const float* Wk          = (const float*)d_in[3];
    const float* Wv          = (const float*)d_in[4];
    const float* q_gamma     = (const float*)d_in[5];
    const float* k_gamma     = (const float*)d_in[6];
    const float* Wo          = (const float*)d_in[7];
    const float* ff_norm_w   = (const float*)d_in[8];
    const float* W_in        = (const float*)d_in[9];
    const float* b_in        = (const float*)d_in[10];
    const float* W_out       = (const float*)d_in[11];
    const float* b_out       = (const float*)d_in[12];
    const float* final_w     = (const float*)d_in[13];

    float* x = (float*)d_out;
    char* ws = (char*)d_ws;

    // per-layer bf16 weight slab (reused each layer)
    bf16* wtqkv = (bf16*)ws;                     // [2048][512]
    bf16* wto   = wtqkv + 2048 * 512;            // [512][1024]
    bf16* wtin  = wto   + 512 * 1024;            // [2816][512] interleaved
    bf16* wtout = wtin  + 2816 * 512;            // [512][1408]
    size_t off = (size_t)(2048*512 + 512*1024 + 2816*512 + 512*1408) * 2;  // 7,471,104
    bf16* h = (bf16*)(ws + off);                 // [N][512]
    off += (size_t)NROWS * 512 * 2;
    char* region = ws + off;
    bf16* qkv = (bf16*)region;                               // [N][2048]  33.7 MB
    bf16* glu = (bf16*)region;                               // [N][1408]  (FF phase alias)
    bf16* vt  = (bf16*)(region + (size_t)NROWS * 2048 * 2);  // [256][64][288]  9.4 MB
    bf16* ob  = (bf16*)(region + (size_t)NROWS * 2048 * 2 + (size_t)256*64*SKP*2);  // [N][1024]

    hipMemcpyAsync(x, tokens, (size_t)NROWS * 512 * 4, hipMemcpyDeviceToDevice, stream);

    for (int l = 0; l < 8; ++l) {
        int is_time = ((l + 1) % 4 == 0) ? 1 : 0;
        wtrans_layer<<<3648, 256, 0, stream>>>(
            Wq + (size_t)l * 512 * 1024, Wk + (size_t)l * 512 * 512,
            Wv + (size_t)l * 512 * 512, Wo + (size_t)l * 1024 * 512,
            W_in + (size_t)l * 512 * DI2, W_out + (size_t)l * DII * 512,
            wtqkv, wto, wtin, wtout);

        // ---- attention block ----
        rms_kernel<1><<<NROWS, 256, 0, stream>>>(x, attn_norm_w + (size_t)l * 512, h, is_time);
        mfma_gemm<1, 0><<<dim3(16, 65), 256, 0, stream>>>(
            h, 512, wtqkv, 512, nullptr, qkv, 2048, 2048, NROWS, 512,
            q_gamma + (size_t)l * 1024, k_gamma + (size_t)l * 512, is_time);
        if (is_time) {
            time_attn_kernel<<<dim3(514, 16), 256, 0, stream>>>(qkv, ob);
            mfma_gemm<3, 1><<<dim3(4, 65), 256, 0, stream>>>(
                ob, 1024, wto, 1024, nullptr, x, 512, 512, NROWS, 1024, nullptr, nullptr, 0);
        } else {
            vtrans_kernel<<<dim3(256, 9), 256, 0, stream>>>(qkv, vt);
            space_attn_kernel<<<dim3(5, 16, 32), 256, 0, stream>>>(qkv, vt, ob);
            mfma_gemm<3, 0><<<dim3(4, 65), 256, 0, stream>>>(
                ob, 1024, wto, 1024, nullptr, x, 512, 512, NROWS, 1024, nullptr, nullptr, 0);
        }

        // ---- feed-forward block ----
        rms_kernel<1><<<NROWS, 256, 0, stream>>>(x, ff_norm_w + (size_t)l * 512, h, 0);
        mfma_gemm<2, 0><<<dim3(22, 65), 256, 0, stream>>>(
            h, 512, wtin, 512, b_in + (size_t)l * DI2, glu, GLULD, FNPAD, NROWS, 512,
            nullptr, nullptr, 0);
        mfma_gemm<3, 0><<<dim3(4, 65), 256, 0, stream>>>(
            glu, GLULD, wtout, GLULD, b_out + (size_t)l * 512, x, 512, 512, NROWS, GLULD,
            nullptr, nullptr, 0);
    }

    rms_kernel<0><<<NROWS, 256, 0, stream>>>(x, final_w, x, 0);
}

// Round 5
// 2584.970 us; speedup vs baseline: 8.6219x; 1.0727x over previous
//
#include <hip/hip_runtime.h>
#include <hip/hip_bf16.h>
#include <math.h>

typedef __attribute__((ext_vector_type(8))) short short8;
typedef __attribute__((ext_vector_type(4))) float f32x4;
typedef __hip_bfloat16 bf16;

#define BB 2
#define TT 16
#define SSQ 257
#define DIMD 512
#define NROWS 8224          // B*T*S
#define DII 1365
#define DI2 2730
#define FNPAD 2816          // ff_in N padded (22*128), interleaved a/g pairs
#define GLULD 1408          // glu row stride / ff_out K (44*32)
#define SKP 288             // padded key count for space attn
#define EPSR 1.1920929e-07f

__device__ __forceinline__ void async16(const void* g, const void* l) {
    __builtin_amdgcn_global_load_lds(
        (const __attribute__((address_space(1))) void*)g,
        (__attribute__((address_space(3))) void*)l, 16, 0, 0);
}

__device__ __forceinline__ short f2bfs(float x) {
    bf16 h = __float2bfloat16(x);
    return *reinterpret_cast<short*>(&h);
}

// ---------------- batched per-layer weight transpose fp32->bf16 ----------------
__global__ void wtrans_layer(const float* __restrict__ wq, const float* __restrict__ wk,
                             const float* __restrict__ wv, const float* __restrict__ wo,
                             const float* __restrict__ win, const float* __restrict__ wout,
                             bf16* __restrict__ dqkv, bf16* __restrict__ dwo,
                             bf16* __restrict__ dwin, bf16* __restrict__ dwout) {
    __shared__ float tile[32][33];
    int bid = blockIdx.x;
    const float* src; bf16* dst; int K, M, Kpad, interleave = 0, local;
    if (bid < 512)       { src = wq;   dst = dqkv;            K = 512;  M = 1024; Kpad = 512;  local = bid; }
    else if (bid < 768)  { src = wk;   dst = dqkv + 1024*512; K = 512;  M = 512;  Kpad = 512;  local = bid - 512; }
    else if (bid < 1024) { src = wv;   dst = dqkv + 1536*512; K = 512;  M = 512;  Kpad = 512;  local = bid - 768; }
    else if (bid < 1536) { src = wo;   dst = dwo;             K = 1024; M = 512;  Kpad = 1024; local = bid - 1024; }
    else if (bid < 2944) { src = win;  dst = dwin;            K = 512;  M = 2730; Kpad = 512;  local = bid - 1536; interleave = 1; }
    else                 { src = wout; dst = dwout;           K = 1365; M = 512;  Kpad = 1408; local = bid - 2944; }
    int tilesx = Kpad >> 5;
    int k0 = (local % tilesx) * 32, m0 = (local / tilesx) * 32;
    int tx = threadIdx.x & 31, ty = threadIdx.x >> 5;
    #pragma unroll
    for (int i = 0; i < 4; ++i) {
        int k = k0 + ty + 8 * i, m = m0 + tx;
        tile[ty + 8 * i][tx] = (k < K && m < M) ? src[(size_t)k * M + m] : 0.f;
    }
    __syncthreads();
    #pragma unroll
    for (int i = 0; i < 4; ++i) {
        int n = m0 + ty + 8 * i, k = k0 + tx;
        int nd = n;
        if (interleave) nd = (n < DII) ? 2 * n : ((n < DI2) ? 2 * (n - DII) + 1 : n);
        dst[(size_t)nd * Kpad + k] = __float2bfloat16(tile[tx][ty + 8 * i]);
    }
}

// ---------------- RMSNorm (optional permuted read (b,t,s)->(b,s,t)) ----------------
template<int BF16OUT>
__global__ void rms_kernel(const float* __restrict__ x, const float* __restrict__ w,
                           void* __restrict__ out, int perm) {
    int r = blockIdx.x;
    int src = r;
    if (perm) {
        int t = r & 15; int rs = r >> 4; int s = rs % SSQ; int b = rs / SSQ;
        src = (b * TT + t) * SSQ + s;
    }
    const float* xr = x + (size_t)src * DIMD;
    int tid = threadIdx.x;
    float v0 = xr[tid], v1 = xr[tid + 256];
    __shared__ float red[256];
    red[tid] = v0 * v0 + v1 * v1;
    __syncthreads();
    for (int st = 128; st; st >>= 1) {
        if (tid < st) red[tid] += red[tid + st];
        __syncthreads();
    }
    float sc = rsqrtf(red[0] * (1.f / DIMD) + EPSR);
    if (BF16OUT) {
        bf16* o = (bf16*)out + (size_t)r * DIMD;
        o[tid] = __float2bfloat16(v0 * sc * w[tid]);
        o[tid + 256] = __float2bfloat16(v1 * sc * w[tid + 256]);
    } else {
        float* o = (float*)out + (size_t)r * DIMD;
        o[tid] = v0 * sc * w[tid];
        o[tid + 256] = v1 * sc * w[tid + 256];
    }
}

// ---------------- MFMA bf16 GEMM: C[nrow,M] = A[nrow,K] @ Bt[M,K]^T ----------------
// TM x 128 tile, BK=32, double-buffered LDS (1 barrier/iter), conflict-free
// granule swizzle kc' = kc ^ ((m>>1)&3). 4 waves. EPI: 1 = qkv + fused
// l2norm/gamma/rotary; 2 = glu (interleaved a/g); 3 = fp32 accumulate.
template<int EPI, int PERM, int TM>
__global__ __launch_bounds__(256)
void mfma_gemm(const bf16* __restrict__ A, int lda,
               const bf16* __restrict__ Bt, int ldb,
               const float* __restrict__ bias,
               void* __restrict__ C, int ldc, int Mstore,
               int nrow, int K,
               const float* __restrict__ qg, const float* __restrict__ kg, int rotary) {
    constexpr int MI = TM / 32;                 // m-frags per wave (4 or 2)
    __shared__ __align__(16) short lds_a[2][TM * 32];
    __shared__ __align__(16) short lds_b[2][128 * 32];
    int tid = threadIdx.x;
    int wave = tid >> 6, lane = tid & 63;
    int quad = lane >> 4, l16 = lane & 15;
    int m0 = blockIdx.y * TM, n0 = blockIdx.x * 128;
    int wm = (wave & 1) * (TM / 2), wn = (wave >> 1) * 64;
    f32x4 zero4 = {0.f, 0.f, 0.f, 0.f};
    f32x4 acc[MI][4];
    #pragma unroll
    for (int i = 0; i < MI; ++i)
        #pragma unroll
        for (int j = 0; j < 4; ++j) acc[i][j] = zero4;

    const short* Ap = (const short*)A;
    const short* Bp = (const short*)Bt;
    // staging granule -> global pointer (granule g holds X[m=g>>2][kc=(g&3)^((g>>3)&3)])
    auto aptr = [&](int g) {
        int m = g >> 2, kc = (g & 3) ^ ((g >> 3) & 3);
        int r = m0 + m; if (r >= nrow) r = nrow - 1;
        return Ap + (size_t)r * lda + kc * 8;
    };
    auto bptr = [&](int g) {
        int m = g >> 2, kc = (g & 3) ^ ((g >> 3) & 3);
        return Bp + (size_t)(n0 + m) * ldb + kc * 8;
    };
    const short* gA0; const short* gA1 = nullptr;
    int aoff0, aoff1 = 0;
    if (TM == 128) {
        gA0 = aptr(wave * 128 + lane);        aoff0 = (wave * 128) * 8;
        gA1 = aptr(wave * 128 + 64 + lane);   aoff1 = (wave * 128 + 64) * 8;
    } else {
        gA0 = aptr(wave * 64 + lane);         aoff0 = (wave * 64) * 8;
    }
    const short* gB0 = bptr(wave * 128 + lane);
    const short* gB1 = bptr(wave * 128 + 64 + lane);
    int boff0 = (wave * 128) * 8, boff1 = (wave * 128 + 64) * 8;

    auto stage = [&](int buf, int kt) {
        int ko = kt * 32;
        async16(gA0 + ko, &lds_a[buf][aoff0]);
        if (TM == 128) async16(gA1 + ko, &lds_a[buf][aoff1]);
        async16(gB0 + ko, &lds_b[buf][boff0]);
        async16(gB1 + ko, &lds_b[buf][boff1]);
    };

    int nk = K >> 5;
    stage(0, 0);
    for (int kt = 0; kt < nk; ++kt) {
        int buf = kt & 1;
        __syncthreads();                       // stage(kt) complete
        if (kt + 1 < nk) stage(buf ^ 1, kt + 1);
        short8 af[MI], bfr[4];
        #pragma unroll
        for (int mi = 0; mi < MI; ++mi) {
            int m = wm + mi * 16 + l16;
            af[mi] = *(const short8*)&lds_a[buf][(m * 4 + (quad ^ ((m >> 1) & 3))) * 8];
        }
        #pragma unroll
        for (int nj = 0; nj < 4; ++nj) {
            int n = wn + nj * 16 + l16;
            bfr[nj] = *(const short8*)&lds_b[buf][(n * 4 + (quad ^ ((n >> 1) & 3))) * 8];
        }
        #pragma unroll
        for (int mi = 0; mi < MI; ++mi)
            #pragma unroll
            for (int nj = 0; nj < 4; ++nj)
                acc[mi][nj] = __builtin_amdgcn_mfma_f32_16x16x32_bf16(
                    af[mi], bfr[nj], acc[mi][nj], 0, 0, 0);
    }

    if constexpr (EPI == 1) {
        // qkv output: cols wn..wn+63 = exactly one head.
        int head = (n0 + wn) >> 6;          // 0..15 q, 16..23 k, 24..31 v
        float gl0 = 0.f, gl1 = 0.f, gl2 = 0.f, gl3 = 0.f, inv0 = 0.f, inv1 = 0.f;
        if (head < 24) {
            const float* g = head < 16 ? qg + head * 64 : kg + (head - 16) * 64;
            gl0 = (g[l16] + 1.f) * 8.f;
            gl1 = (g[16 + l16] + 1.f) * 8.f;
            gl2 = (g[32 + l16] + 1.f) * 8.f;
            gl3 = (g[48 + l16] + 1.f) * 8.f;
            if (rotary) {
                inv0 = __expf(-(float)l16 * 0.28782313662425572f);        // ln(1e4)/32
                inv1 = __expf(-(float)(l16 + 16) * 0.28782313662425572f);
            }
        }
        #pragma unroll
        for (int mi = 0; mi < MI; ++mi) {
            #pragma unroll
            for (int e = 0; e < 4; ++e) {
                int row = m0 + wm + mi * 16 + quad * 4 + e;
                float v0 = acc[mi][0][e], v1 = acc[mi][1][e];
                float v2 = acc[mi][2][e], v3 = acc[mi][3][e];
                if (head < 24) {
                    float ss = v0 * v0 + v1 * v1 + v2 * v2 + v3 * v3;
                    ss += __shfl_xor(ss, 1); ss += __shfl_xor(ss, 2);
                    ss += __shfl_xor(ss, 4); ss += __shfl_xor(ss, 8);
                    float invn = 1.f / fmaxf(sqrtf(ss), 1e-12f);
                    v0 *= invn * gl0; v1 *= invn * gl1;
                    v2 *= invn * gl2; v3 *= invn * gl3;
                    if (rotary) {
                        float t = (float)(row & 15);
                        float a0 = t * inv0, a1 = t * inv1;
                        float c0 = __cosf(a0), s0 = __sinf(a0);
                        float c1 = __cosf(a1), s1 = __sinf(a1);
                        float n0v = v0 * c0 - v2 * s0;
                        float n1v = v1 * c1 - v3 * s1;
                        float n2v = v2 * c0 + v0 * s0;
                        float n3v = v3 * c1 + v1 * s1;
                        v0 = n0v; v1 = n1v; v2 = n2v; v3 = n3v;
                    }
                }
                if (row < nrow) {
                    bf16* p = (bf16*)C + (size_t)row * ldc + n0 + wn + l16;
                    p[0]  = __float2bfloat16(v0);
                    p[16] = __float2bfloat16(v1);
                    p[32] = __float2bfloat16(v2);
                    p[48] = __float2bfloat16(v3);
                }
            }
        }
    } else if constexpr (EPI == 2) {
        // interleaved a/g: even col = a, odd col = g; write glu at col/2.
        #pragma unroll
        for (int mi = 0; mi < MI; ++mi) {
            #pragma unroll
            for (int e = 0; e < 4; ++e) {
                int row = m0 + wm + mi * 16 + quad * 4 + e;
                #pragma unroll
                for (int nj = 0; nj < 4; ++nj) {
                    int col = n0 + wn + nj * 16 + l16;
                    int j = col >> 1;
                    float b = (j < DII) ? ((col & 1) ? bias[DII + j] : bias[j]) : 0.f;
                    float v = acc[mi][nj][e] + b;
                    float prt = __shfl_xor(v, 1);
                    if (!(l16 & 1) && row < nrow) {
                        float gv = prt;
                        float glu = v * 0.5f * gv * (1.f + erff(gv * 0.70710678118654752f));
                        ((bf16*)C)[(size_t)row * ldc + j] = __float2bfloat16(glu);
                    }
                }
            }
        }
    } else {
        #pragma unroll
        for (int mi = 0; mi < MI; ++mi) {
            #pragma unroll
            for (int e = 0; e < 4; ++e) {
                int row = m0 + wm + mi * 16 + quad * 4 + e;
                if (row >= nrow) continue;
                int orow = row;
                if (PERM) {
                    int t = row & 15; int rs = row >> 4; int s = rs % SSQ; int b = rs / SSQ;
                    orow = (b * TT + t) * SSQ + s;
                }
                #pragma unroll
                for (int nj = 0; nj < 4; ++nj) {
                    int col = n0 + wn + nj * 16 + l16;
                    if (col >= Mstore) continue;
                    float v = acc[mi][nj][e];
                    if (bias) v += bias[col];
                    ((float*)C)[(size_t)orow * ldc + col] += v;
                }
            }
        }
    }
}

// ---------------- V transpose for PV MFMA: vt[bt*8+kh][64][SKP] bf16 ----------------
__global__ void vtrans_kernel(const bf16* __restrict__ qkv, bf16* __restrict__ vt) {
    int bkh = blockIdx.x;          // bt*8 + kh
    int kc = blockIdx.y;           // key chunk of 32
    int bt = bkh >> 3, kh = bkh & 7;
    int tid = threadIdx.x;
    #pragma unroll
    for (int i = 0; i < 8; ++i) {
        int idx = tid + 256 * i;   // 0..2047
        int kl = idx >> 6;         // key local
        int d = idx & 63;
        int key = kc * 32 + kl;
        float v = 0.f;
        if (key < SSQ)
            v = __bfloat162float(qkv[((size_t)(bt * SSQ + key)) * 2048 + 1536 + kh * 64 + d]);
        vt[((size_t)bkh * 64 + d) * SKP + key] = __float2bfloat16(v);
    }
}

// ---------------- space attention: S^T in registers, zero LDS ----------------
__global__ __launch_bounds__(256)
void space_attn_kernel(const bf16* __restrict__ qkv, const bf16* __restrict__ vt,
                       bf16* __restrict__ ob) {
    int qt = blockIdx.x, qh = blockIdx.y, bt = blockIdx.z;
    int kh = qh >> 1;
    int tid = threadIdx.x, wave = tid >> 6, lane = tid & 63;
    int quad = lane >> 4, l16 = lane & 15;
    int q0w = qt * 64 + wave * 16;
    int q = q0w + l16;
    int qc = q > 256 ? 256 : q;
    const short* qbase = (const short*)qkv + (size_t)bt * SSQ * 2048;
    const short* qp = qbase + (size_t)qc * 2048 + qh * 64;
    short8 bq0 = *(const short8*)(qp + quad * 8);
    short8 bq1 = *(const short8*)(qp + 32 + quad * 8);
    f32x4 zero4 = {0.f, 0.f, 0.f, 0.f};
    f32x4 sc[18];

    #pragma unroll
    for (int kt = 0; kt < 17; ++kt) {
        int keyl = kt * 16 + l16; if (keyl > 256) keyl = 256;
        const short* kp = qbase + (size_t)keyl * 2048 + 1024 + kh * 64;
        short8 ak0 = *(const short8*)(kp + quad * 8);
        short8 ak1 = *(const short8*)(kp + 32 + quad * 8);
        f32x4 c = zero4;
        c = __builtin_amdgcn_mfma_f32_16x16x32_bf16(ak0, bq0, c, 0, 0, 0);
        c = __builtin_amdgcn_mfma_f32_16x16x32_bf16(ak1, bq1, c, 0, 0, 0);
        #pragma unroll
        for (int e = 0; e < 4; ++e) {
            float e2x = __expf(c[e] * 0.005f);
            float v = 50.f - 100.f * __builtin_amdgcn_rcpf(e2x + 1.f);
            if (kt == 16) {
                bool valid = (e == 0) && (quad == 0) && (q == 256);
                v = valid ? v : -1e30f;
            }
            c[e] = v;
        }
        sc[kt] = c;
    }

    float mx = -1e30f;
    #pragma unroll
    for (int kt = 0; kt < 17; ++kt)
        mx = fmaxf(mx, fmaxf(fmaxf(sc[kt][0], sc[kt][1]), fmaxf(sc[kt][2], sc[kt][3])));
    mx = fmaxf(mx, __shfl_xor(mx, 16));
    mx = fmaxf(mx, __shfl_xor(mx, 32));
    float sum = 0.f;
    #pragma unroll
    for (int kt = 0; kt < 17; ++kt) {
        #pragma unroll
        for (int e = 0; e < 4; ++e) {
            float p = __expf(sc[kt][e] - mx);
            sc[kt][e] = p;
            sum += p;
        }
    }
    #pragma unroll
    for (int e = 0; e < 4; ++e) sc[17][e] = 0.f;
    sum += __shfl_xor(sum, 16);
    sum += __shfl_xor(sum, 32);
    float inv = __builtin_amdgcn_rcpf(sum);
    f32x4 inv4;
    #pragma unroll
    for (int e = 0; e < 4; ++e) inv4[e] = __shfl(inv, quad * 4 + e);

    f32x4 oacc[4];
    #pragma unroll
    for (int nt = 0; nt < 4; ++nt) oacc[nt] = zero4;
    const short* vbp = (const short*)vt + ((size_t)(bt * 8 + kh) * 64 + l16) * SKP;
    #pragma unroll
    for (int c8 = 0; c8 < 9; ++c8) {
        short8 pb;
        #pragma unroll
        for (int j = 0; j < 8; ++j) {
            int src_lane = ((quad & 1) * 2 + (j >> 2)) * 16 + l16;
            float v0 = __shfl(sc[2 * c8][j & 3], src_lane);
            float v1 = __shfl(sc[2 * c8 + 1][j & 3], src_lane);
            pb[j] = f2bfs(quad < 2 ? v0 : v1);
        }
        #pragma unroll
        for (int nt = 0; nt < 4; ++nt) {
            short8 av = *(const short8*)(vbp + (size_t)(nt * 16) * SKP + c8 * 32 + quad * 8);
            oacc[nt] = __builtin_amdgcn_mfma_f32_16x16x32_bf16(pb, av, oacc[nt], 0, 0, 0);
        }
    }

    #pragma unroll
    for (int e = 0; e < 4; ++e) {
        int qq = q0w + quad * 4 + e;
        if (qq <= 256) {
            bf16* op = ob + ((size_t)(bt * SSQ + qq)) * 1024 + qh * 64 + l16;
            float s = inv4[e];
            op[0]  = __float2bfloat16(oacc[0][e] * s);
            op[16] = __float2bfloat16(oacc[1][e] * s);
            op[32] = __float2bfloat16(oacc[2][e] * s);
            op[48] = __float2bfloat16(oacc[3][e] * s);
        }
    }
}

// ---------------- time attention (n=16, causal): one block per (b*s, qh) ----------------
__global__ void time_attn_kernel(const bf16* __restrict__ qkv, bf16* __restrict__ ob) {
    __shared__ float qs[16][65], ks[16][65], ps[16][17];
    int bs = blockIdx.x, qh = blockIdx.y, kh = qh >> 1;
    int tid = threadIdx.x;
    size_t rowbase = (size_t)bs * 16;
    #pragma unroll
    for (int i = 0; i < 4; ++i) {
        int idx = tid + 256 * i;
        int r = idx >> 6, d = idx & 63;
        qs[r][d] = __bfloat162float(qkv[(rowbase + r) * 2048 + qh * 64 + d]);
        ks[r][d] = __bfloat162float(qkv[(rowbase + r) * 2048 + 1024 + kh * 64 + d]);
    }
    __syncthreads();
    int i = tid >> 4, j = tid & 15;
    float dot = 0.f;
    #pragma unroll 16
    for (int d = 0; d < 64; ++d) dot += qs[i][d] * ks[j][d];
    float s = dot * 0.125f;
    float ex = __expf(s * 0.04f);
    s = 50.f * (ex - 1.f) / (ex + 1.f);
    if (j > i) s = -1e30f;
    float mx = s;
    mx = fmaxf(mx, __shfl_xor(mx, 1));
    mx = fmaxf(mx, __shfl_xor(mx, 2));
    mx = fmaxf(mx, __shfl_xor(mx, 4));
    mx = fmaxf(mx, __shfl_xor(mx, 8));
    float p = __expf(s - mx);
    float sum = p;
    sum += __shfl_xor(sum, 1);
    sum += __shfl_xor(sum, 2);
    sum += __shfl_xor(sum, 4);
    sum += __shfl_xor(sum, 8);
    ps[i][j] = p / sum;
    __syncthreads();
    #pragma unroll
    for (int ii = 0; ii < 4; ++ii) {
        int idx = tid + 256 * ii;
        int r = idx >> 6, d = idx & 63;
        float acc = 0.f;
        #pragma unroll
        for (int jj = 0; jj < 16; ++jj)
            acc += ps[r][jj] * __bfloat162float(qkv[(rowbase + jj) * 2048 + 1536 + kh * 64 + d]);
        ob[(rowbase + r) * 1024 + qh * 64 + d] = __float2bfloat16(acc);
    }
}

// ---------------- host-side launch ----------------
extern "C" void kernel_launch(void* const* d_in, const int* in_sizes, int n_in,
                              void* d_out, int out_size, void* d_ws, size_t ws_size,
                              hipStream_t stream) {
    const float* tokens      = (const float*)d_in[0];
    const float* attn_norm_w = (const float*)d_in[1];
    const float* Wq          = (const float*)d_in[2];
    const float* Wk          = (const float*)d_in[3];
    const float* Wv          = (const float*)d_in[4];
    const float* q_gamma     = (const float*)d_in[5];
    const float* k_gamma     = (const float*)d_in[6];
    const float* Wo          = (const float*)d_in[7];
    const float* ff_norm_w   = (const float*)d_in[8];
    const float* W_in        = (const float*)d_in[9];
    const float* b_in        = (const float*)d_in[10];
    const float* W_out       = (const float*)d_in[11];
    const float* b_out       = (const float*)d_in[12];
    const float* final_w     = (const float*)d_in[13];

    float* x = (float*)d_out;
    char* ws = (char*)d_ws;

    bf16* wtqkv = (bf16*)ws;                     // [2048][512]
    bf16* wto   = wtqkv + 2048 * 512;            // [512][1024]
    bf16* wtin  = wto   + 512 * 1024;            // [2816][512] interleaved
    bf16* wtout = wtin  + 2816 * 512;            // [512][1408]
    size_t off = (size_t)(2048*512 + 512*1024 + 2816*512 + 512*1408) * 2;
    bf16* h = (bf16*)(ws + off);                 // [N][512]
    off += (size_t)NROWS * 512 * 2;
    char* region = ws + off;
    bf16* qkv = (bf16*)region;                               // [N][2048]
    bf16* glu = (bf16*)region;                               // [N][1408] (FF alias)
    bf16* vt  = (bf16*)(region + (size_t)NROWS * 2048 * 2);  // [256][64][288]
    bf16* ob  = (bf16*)(region + (size_t)NROWS * 2048 * 2 + (size_t)256*64*SKP*2);  // [N][1024]

    hipMemcpyAsync(x, tokens, (size_t)NROWS * 512 * 4, hipMemcpyDeviceToDevice, stream);

    for (int l = 0; l < 8; ++l) {
        int is_time = ((l + 1) % 4 == 0) ? 1 : 0;
        wtrans_layer<<<3648, 256, 0, stream>>>(
            Wq + (size_t)l * 512 * 1024, Wk + (size_t)l * 512 * 512,
            Wv + (size_t)l * 512 * 512, Wo + (size_t)l * 1024 * 512,
            W_in + (size_t)l * 512 * DI2, W_out + (size_t)l * DII * 512,
            wtqkv, wto, wtin, wtout);

        // ---- attention block ----
        rms_kernel<1><<<NROWS, 256, 0, stream>>>(x, attn_norm_w + (size_t)l * 512, h, is_time);
        mfma_gemm<1, 0, 128><<<dim3(16, 65), 256, 0, stream>>>(
            h, 512, wtqkv, 512, nullptr, qkv, 2048, 2048, NROWS, 512,
            q_gamma + (size_t)l * 1024, k_gamma + (size_t)l * 512, is_time);
        if (is_time) {
            time_attn_kernel<<<dim3(514, 16), 256, 0, stream>>>(qkv, ob);
            mfma_gemm<3, 1, 64><<<dim3(4, 129), 256, 0, stream>>>(
                ob, 1024, wto, 1024, nullptr, x, 512, 512, NROWS, 1024, nullptr, nullptr, 0);
        } else {
            vtrans_kernel<<<dim3(256, 9), 256, 0, stream>>>(qkv, vt);
            space_attn_kernel<<<dim3(5, 16, 32), 256, 0, stream>>>(qkv, vt, ob);
            mfma_gemm<3, 0, 64><<<dim3(4, 129), 256, 0, stream>>>(
                ob, 1024, wto, 1024, nullptr, x, 512, 512, NROWS, 1024, nullptr, nullptr, 0);
        }

        // ---- feed-forward block ----
        rms_kernel<1><<<NROWS, 256, 0, stream>>>(x, ff_norm_w + (size_t)l * 512, h, 0);
        mfma_gemm<2, 0, 128><<<dim3(22, 65), 256, 0, stream>>>(
            h, 512, wtin, 512, b_in + (size_t)l * DI2, glu, GLULD, FNPAD, NROWS, 512,
            nullptr, nullptr, 0);
        mfma_gemm<3, 0, 64><<<dim3(4, 129), 256, 0, stream>>>(
            glu, GLULD, wtout, GLULD, b_out + (size_t)l * 512, x, 512, 512, NROWS, GLULD,
            nullptr, nullptr, 0);
    }

    rms_kernel<0><<<NROWS, 256, 0, stream>>>(x, final_w, x, 0);
}